// Round 6
// baseline (336.451 us; speedup 1.0000x reference)
//
#include <hip/hip_runtime.h>
#include <math.h>

#define ROWS 64
#define TLEN 64000
#define NFR 251
#define NMELS 80
#define NFB 131072            // big FFT length (>= 2*T-1 -> exact linear conv)
#define PI2F 6.28318530717958647692f
#define PI_F 3.14159265358979323846f

// banked double accumulators:
// 0 S_dt  1 S_rt  2 S_sp  3..6 E0..E3  7 S_mag  8 S_cos  9 S_mel  10 S_c
__device__ double g_part[64][12];

// slot holding k2 after per-lane radix-4 FFT16 (digit reversal, involution)
__device__ constexpr int DR[16] = {0,4,8,12,1,5,9,13,2,6,10,14,3,7,11,15};
// mirror slot: RM[r] = DR[16 - DR[r]]
__device__ constexpr int RM[16] = {0,3,2,1,15,14,13,12,11,10,9,8,7,6,5,4};

__device__ inline int dr4(int i){ return ((i & 3) << 2) | (i >> 2); }  // DR, runtime
// bank-conflict-free swizzle for stride-16 writes into 513-entry arrays
__device__ inline int SW(int k){ return k + (k >> 5); }

__device__ inline void atomAddD(double* p, double v){
  __hip_atomic_fetch_add(p, v, __ATOMIC_RELAXED, __HIP_MEMORY_SCOPE_AGENT);
}
__device__ inline int brev6(int x){ return (int)((unsigned)__brev((unsigned)x) >> 26); }
__device__ inline float2 cmul(float2 a, float2 b){
  return make_float2(a.x*b.x - a.y*b.y, a.x*b.y + a.y*b.x);
}
__device__ inline float wred(float v){
#pragma unroll
  for (int o = 32; o > 0; o >>= 1) v += __shfl_down(v, o, 64);
  return v;
}

// wave-local LDS fence: DS traffic inside fft64_lds is per-wave cross-lane ->
// only this wave's lgkmcnt needs draining, NOT a workgroup barrier.
__device__ inline void wave_fence(){
  asm volatile("s_waitcnt lgkmcnt(0)" ::: "memory");
}

// ---------- shuffle cross-lane FFT (kept only for the 128-pt path in k_mid) ----------
template<int S, int N>
__device__ inline void fft64_lanes(float2* v, int l){
  float2 W[5];
#pragma unroll
  for (int si = 0; si < 5; ++si){
    int d = 32 >> si;
    float a = (float)S * PI_F * (float)(l & (d-1)) * (1.0f/(float)d);
    float sn, cs; __sincosf(a, &sn, &cs);
    W[si] = make_float2(cs, sn);
  }
#pragma unroll
  for (int si = 0; si < 6; ++si){
    int d = 32 >> si;
    bool hi = (l & d) != 0;
#pragma unroll
    for (int rr = 0; rr < N; ++rr){
      float2 x = v[rr];
      float tx = __shfl_xor(x.x, d, 64);
      float ty = __shfl_xor(x.y, d, 64);
      float sx = x.x + tx, sy = x.y + ty;
      float dx = tx - x.x, dy = ty - x.y;
      float rx, ry;
      if (si < 5){ rx = dx*W[si].x - dy*W[si].y; ry = dx*W[si].y + dy*W[si].x; }
      else       { rx = dx; ry = dy; }
      v[rr].x = hi ? rx : sx;
      v[rr].y = hi ? ry : sy;
    }
  }
}

template<int S>
__device__ inline void fft16_reg(float2* v){
  const float Sf = (float)S;
  const float C1 = 0.9238795325112867f, S1 = 0.3826834323650898f, C2 = 0.7071067811865476f;
  const float2 W1[4] = {{1.f,0.f},{C1,Sf*S1},{C2,Sf*C2},{S1,Sf*C1}};
  const float2 W2[4] = {{1.f,0.f},{C2,Sf*C2},{0.f,Sf},{-C2,Sf*C2}};
  const float2 W3[4] = {{1.f,0.f},{S1,Sf*C1},{-C2,Sf*C2},{-C1,-Sf*S1}};
#pragma unroll
  for (int j = 0; j < 4; ++j){
    float2 x0=v[j], x1=v[j+4], x2=v[j+8], x3=v[j+12];
    float2 t0={x0.x+x2.x, x0.y+x2.y}, t1={x0.x-x2.x, x0.y-x2.y};
    float2 t2={x1.x+x3.x, x1.y+x3.y}, t3={x1.x-x3.x, x1.y-x3.y};
    float2 y0={t0.x+t2.x, t0.y+t2.y};
    float2 y2={t0.x-t2.x, t0.y-t2.y};
    float2 y1={t1.x - Sf*t3.y, t1.y + Sf*t3.x};
    float2 y3={t1.x + Sf*t3.y, t1.y - Sf*t3.x};
    v[j]=y0; v[j+4]=cmul(y1,W1[j]); v[j+8]=cmul(y2,W2[j]); v[j+12]=cmul(y3,W3[j]);
  }
#pragma unroll
  for (int b = 0; b < 4; ++b){
    float2 x0=v[4*b], x1=v[4*b+1], x2=v[4*b+2], x3=v[4*b+3];
    float2 t0={x0.x+x2.x, x0.y+x2.y}, t1={x0.x-x2.x, x0.y-x2.y};
    float2 t2={x1.x+x3.x, x1.y+x3.y}, t3={x1.x-x3.x, x1.y-x3.y};
    v[4*b]   = make_float2(t0.x+t2.x, t0.y+t2.y);
    v[4*b+2] = make_float2(t0.x-t2.x, t0.y-t2.y);
    v[4*b+1] = make_float2(t1.x - Sf*t3.y, t1.y + Sf*t3.x);
    v[4*b+3] = make_float2(t1.x + Sf*t3.y, t1.y - Sf*t3.x);
  }
}

// 128-pt forward: input v[m]=x[l+64m]; output slot rr, lane l = X[rr+2*brev6(l)]
template<int S>
__device__ inline void fft128_wave(float2* v, int l){
  float2 a = {v[0].x+v[1].x, v[0].y+v[1].y};
  float2 b = {v[0].x-v[1].x, v[0].y-v[1].y};
  float ang = (float)S * PI_F * (float)l * (1.0f/64.0f);
  float sn, cs; __sincosf(ang, &sn, &cs);
  v[0] = a; v[1] = cmul(b, make_float2(cs, sn));
  fft64_lanes<S,2>(v, l);
}

// ---------- LDS-based cross-lane 64-FFT (four-step 8x8), natural in/out ----------
template<int S>
__device__ inline void fft8p(float2* y){
  const float Sf = (float)S;
  const float C2 = 0.7071067811865476f;
  float2 t0={y[0].x+y[4].x, y[0].y+y[4].y};
  float2 t1={y[1].x+y[5].x, y[1].y+y[5].y};
  float2 t2={y[2].x+y[6].x, y[2].y+y[6].y};
  float2 t3={y[3].x+y[7].x, y[3].y+y[7].y};
  float2 u0={y[0].x-y[4].x, y[0].y-y[4].y};
  float2 u1={y[1].x-y[5].x, y[1].y-y[5].y};
  float2 u2={y[2].x-y[6].x, y[2].y-y[6].y};
  float2 u3={y[3].x-y[7].x, y[3].y-y[7].y};
  { float x=u1.x, yy=u1.y; u1.x = C2*(x - Sf*yy); u1.y = C2*(Sf*x + yy); }
  { float x=u2.x, yy=u2.y; u2.x = -Sf*yy;         u2.y = Sf*x; }
  { float x=u3.x, yy=u3.y; u3.x = -C2*(x + Sf*yy); u3.y = C2*(Sf*x - yy); }
  {
    float2 e0={t0.x+t2.x,t0.y+t2.y}, e1={t0.x-t2.x,t0.y-t2.y};
    float2 o0={t1.x+t3.x,t1.y+t3.y}, o1={t1.x-t3.x,t1.y-t3.y};
    y[0]=make_float2(e0.x+o0.x, e0.y+o0.y);
    y[4]=make_float2(e0.x-o0.x, e0.y-o0.y);
    y[2]=make_float2(e1.x - Sf*o1.y, e1.y + Sf*o1.x);
    y[6]=make_float2(e1.x + Sf*o1.y, e1.y - Sf*o1.x);
  }
  {
    float2 e0={u0.x+u2.x,u0.y+u2.y}, e1={u0.x-u2.x,u0.y-u2.y};
    float2 o0={u1.x+u3.x,u1.y+u3.y}, o1={u1.x-u3.x,u1.y-u3.y};
    y[1]=make_float2(e0.x+o0.x, e0.y+o0.y);
    y[5]=make_float2(e0.x-o0.x, e0.y-o0.y);
    y[3]=make_float2(e1.x - Sf*o1.y, e1.y + Sf*o1.x);
    y[7]=make_float2(e1.x + Sf*o1.y, e1.y - Sf*o1.x);
  }
}

// 16 independent 64-pt FFTs across lanes, natural order, per-wave 4KB scratch.
template<int S>
__device__ inline void fft64_lds(float2* v, int l, float2* scr){
  int s = l >> 3, a = l & 7;
  int sw = (s & 1);
#pragma unroll
  for (int h = 0; h < 2; ++h){
    float2* vh = v + 8*h;
#pragma unroll
    for (int r = 0; r < 8; ++r) scr[r*64 + l] = vh[r];
    wave_fence();
    float2 y[8];
#pragma unroll
    for (int j = 0; j < 8; ++j)
      y[j] = scr[s*64 + a + 8*((j + s) & 7)];
    fft8p<S>(y);
    {
      float ang = (float)S * PI2F * (float)l * (1.0f/64.0f);
      float sn, cs; __sincosf(ang, &sn, &cs);
      float2 b1 = make_float2(cs, sn), cur = b1;
#pragma unroll
      for (int c = 1; c < 8; ++c){
        y[c] = cmul(y[c], cur);
        if (c < 7) cur = cmul(cur, b1);
      }
    }
    wave_fence();
#pragma unroll
    for (int c = 0; c < 8; ++c)
      scr[s*64 + a + 8*(c ^ sw)] = y[c];
    wave_fence();
    float2 z[8];
#pragma unroll
    for (int j = 0; j < 8; ++j)
      z[j] = scr[s*64 + ((j + s) & 7) + 8*(a ^ sw)];
    fft8p<S>(z);
    {
      float ang2 = (float)S * PI2F * (float)s * 0.125f;
      float sn2, cs2; __sincosf(ang2, &sn2, &cs2);
      float2 b2 = make_float2(cs2, sn2), cur = b2;
#pragma unroll
      for (int d = 1; d < 8; ++d){
        z[d] = cmul(z[d], cur);
        if (d < 7) cur = cmul(cur, b2);
      }
    }
    wave_fence();
#pragma unroll
    for (int d = 0; d < 8; ++d)
      scr[s*64 + a + 8*(d ^ sw)] = z[d];
    wave_fence();
#pragma unroll
    for (int r = 0; r < 8; ++r)
      vh[r] = scr[r*64 + (l ^ ((r & 1) << 3))];
    wave_fence();
  }
}

// 1024-pt forward via LDS: input v[m]=x[l+64m]; output slot rr, lane l =
// X[DR[rr] + 16*l]   (NATURAL lane order)
template<int S>
__device__ inline void fft1024_lds(float2* v, int l, float2* scr){
  fft16_reg<S>(v);
  float a = (float)S * PI2F * (float)l * (1.0f/1024.0f);
  float sn, cs; __sincosf(a, &sn, &cs);
  float2 T = make_float2(cs, sn);
  float2 cur = T;
#pragma unroll
  for (int k2 = 1; k2 < 16; ++k2){
    v[DR[k2]] = cmul(v[DR[k2]], cur);
    if (k2 < 15) cur = cmul(cur, T);
  }
  fft64_lds<S>(v, l, scr);
}

__device__ inline void r4p(float2* v, int i0, int i1, int i2, int i3){
  float2 x0=v[i0], x1=v[i1], x2=v[i2], x3=v[i3];
  float2 t0={x0.x+x2.x, x0.y+x2.y}, t1={x0.x-x2.x, x0.y-x2.y};
  float2 t2={x1.x+x3.x, x1.y+x3.y}, t3={x1.x-x3.x, x1.y-x3.y};
  v[i0] = make_float2(t0.x+t2.x, t0.y+t2.y);
  v[i2] = make_float2(t0.x-t2.x, t0.y-t2.y);
  v[i1] = make_float2(t1.x - t3.y, t1.y + t3.x);
  v[i3] = make_float2(t1.x + t3.y, t1.y - t3.x);
}

__device__ inline void ifft16_reg(float2* v){
#pragma unroll
  for (int b = 0; b < 4; ++b) r4p(v, 4*b, 4*b+1, 4*b+2, 4*b+3);
  const float C1 = 0.9238795325112867f, S1 = 0.3826834323650898f, C2 = 0.7071067811865476f;
  const float2 W1[4] = {{1.f,0.f},{C1,S1},{C2,C2},{S1,C1}};
  const float2 W2[4] = {{1.f,0.f},{C2,C2},{0.f,1.f},{-C2,C2}};
  const float2 W3[4] = {{1.f,0.f},{S1,C1},{-C2,C2},{-C1,-S1}};
#pragma unroll
  for (int j = 1; j < 4; ++j){
    v[j+4]  = cmul(v[j+4],  W1[j]);
    v[j+8]  = cmul(v[j+8],  W2[j]);
    v[j+12] = cmul(v[j+12], W3[j]);
  }
#pragma unroll
  for (int j = 0; j < 4; ++j) r4p(v, j, j+4, j+8, j+12);
}

__device__ inline void ifft1024_lds(float2* v, int l, float2* scr){
  fft64_lds<1>(v, l, scr);            // inverse 64-FFT over lanes, natural order
  float a = PI2F * (float)l * (1.0f/1024.0f);
  float sn, cs; __sincosf(a, &sn, &cs);
  float2 T = make_float2(cs, sn);
  float2 cur = T;
#pragma unroll
  for (int k2 = 1; k2 < 16; ++k2){
    v[DR[k2]] = cmul(v[DR[k2]], cur);
    if (k2 < 15) cur = cmul(cur, T);
  }
  ifft16_reg(v);
}

// ---------- adjoint inverse 64 over lanes (shuffle, for k_mid's 128 path) ----------
template<int N>
__device__ inline void ifft64_lanes(float2* v, int l){
  float2 W[5];
#pragma unroll
  for (int si = 0; si < 5; ++si){
    int d = 32 >> si;
    float a = PI_F * (float)(l & (d-1)) * (1.0f/(float)d);   // conj of forward
    float sn, cs; __sincosf(a, &sn, &cs);
    W[si] = make_float2(cs, sn);
  }
#pragma unroll
  for (int si = 5; si >= 0; --si){
    int d = 32 >> si;
    bool hi = (l & d) != 0;
#pragma unroll
    for (int rr = 0; rr < N; ++rr){
      float2 x = v[rr];
      float2 xp = x;
      if (si < 5 && hi) xp = cmul(x, W[si]);
      float tx = __shfl_xor(xp.x, d, 64);
      float ty = __shfl_xor(xp.y, d, 64);
      v[rr].x = hi ? (tx - xp.x) : (xp.x + tx);
      v[rr].y = hi ? (ty - xp.y) : (xp.y + ty);
    }
  }
}

// input slot rr, lane l = X[rr+2*brev6(l)]; output v[m], lane l = 128*x[l+64m]
__device__ inline void ifft128_wave(float2* v, int l){
  ifft64_lanes<2>(v, l);
  float ang = PI_F * (float)l * (1.0f/64.0f);
  float sn, cs; __sincosf(ang, &sn, &cs);
  v[1] = cmul(v[1], make_float2(cs, sn));
  float2 a = {v[0].x+v[1].x, v[0].y+v[1].y};
  float2 b = {v[0].x-v[1].x, v[0].y-v[1].y};
  v[0] = a; v[1] = b;
}

// ---------------- init: zero accumulators ----------------
extern "C" __global__ void __launch_bounds__(256) k_init(){
  int t = blockIdx.x*256 + threadIdx.x;
  if (t < 768) ((double*)g_part)[t] = 0.0;
}

// ---------------- time-domain losses + rir segment energies (float4) -------
extern "C" __global__ void __launch_bounds__(256) k_time(
    const float* __restrict__ pd, const float* __restrict__ td,
    const float* __restrict__ pr, const float* __restrict__ tr){
  const int N4 = ROWS*TLEN/4;          // 1,024,000 float4s; 16000 per row
  int stride = gridDim.x * 256;
  float sdt=0.f, srt=0.f, ssp=0.f, e0=0.f, e1=0.f, e2=0.f, e3=0.f;
  const float4* pd4 = (const float4*)pd;
  const float4* td4 = (const float4*)td;
  const float4* pr4 = (const float4*)pr;
  const float4* tr4 = (const float4*)tr;
  for (int i = blockIdx.x*256 + threadIdx.x; i < N4; i += stride){
    float4 a = pd4[i], b = td4[i], p = pr4[i], q = tr4[i];
    sdt += fabsf(a.x-b.x)+fabsf(a.y-b.y)+fabsf(a.z-b.z)+fabsf(a.w-b.w);
    srt += fabsf(p.x-q.x)+fabsf(p.y-q.y)+fabsf(p.z-q.z)+fabsf(p.w-q.w);
    ssp += fabsf(p.x)+fabsf(p.y)+fabsf(p.z)+fabsf(p.w);
    float p2 = p.x*p.x + p.y*p.y + p.z*p.z + p.w*p.w;
    int seg = (i % 16000) / 4000;      // uniform for all 4 elems
    if (seg == 0) e0 += p2; else if (seg == 1) e1 += p2;
    else if (seg == 2) e2 += p2; else e3 += p2;
  }
  sdt = wred(sdt); srt = wred(srt); ssp = wred(ssp);
  e0 = wred(e0); e1 = wred(e1); e2 = wred(e2); e3 = wred(e3);
  if ((threadIdx.x & 63) == 0){
    int bank = (blockIdx.x*4 + (threadIdx.x >> 6)) & 63;
    atomAddD(&g_part[bank][0], (double)sdt);
    atomAddD(&g_part[bank][1], (double)srt);
    atomAddD(&g_part[bank][2], (double)ssp);
    atomAddD(&g_part[bank][3], (double)e0);
    atomAddD(&g_part[bank][4], (double)e1);
    atomAddD(&g_part[bank][5], (double)e2);
    atomAddD(&g_part[bank][6], (double)e3);
  }
}

// ---------------- fused STFT (freq + mel) losses, ONE WAVE PER BLOCK --------
extern "C" __global__ void __launch_bounds__(64) k_stft(
    const float* __restrict__ pd, const float* __restrict__ td){
  __shared__ float2 scr[512];             // 4KB four-step scratch
  __shared__ float2 spec0[64];
  __shared__ float2 pt[530];              // (pp,tt) pairs, swizzled SW(k)=k+(k>>5)
  int l = threadIdx.x;
  // XCD-aware swizzle: 16064 = 8*2008 exactly; consecutive frames on same XCD
  int frame = (blockIdx.x & 7) * (ROWS*NFR/8) + (blockIdx.x >> 3);
  int r = frame / NFR, fr = frame - r*NFR;
  const float* pdr = pd + (size_t)r*TLEN;
  const float* tdr = td + (size_t)r*TLEN;
  const float scale = 0.05103103630798288f;   // 1/sqrt(384), folded into window
  int base = fr*256 - 512;
  float2 v[16];
#pragma unroll
  for (int m = 0; m < 16; ++m){
    int j = l + 64*m;
    int g = base + j;
    g = (g < 0) ? -g : ((g >= TLEN) ? (2*TLEN - 2 - g) : g);
    float w = (0.5f - 0.5f*__cosf((PI2F/1024.0f)*(float)j)) * scale;
    v[m] = make_float2(pdr[g]*w, tdr[g]*w);
  }
  fft1024_lds<-1>(v, l, scr);
  // output: slot rr, lane l = X[DR[rr] + 16*l]  (natural lane order)
  spec0[l] = v[0];          // the k2=0 line: Z[16*k1] at index k1
  float magp = 0.f, cosp = 0.f;
  // k2 = 1..15 lines: mirror of (slot rr, lane l) is (slot RM[rr], lane l^63).
#pragma unroll
  for (int rr = 1; rr < 16; ++rr){
    float2 z = v[rr];
    float2 zm;
    zm.x = __shfl_xor(v[RM[rr]].x, 63, 64);
    zm.y = __shfl_xor(v[RM[rr]].y, 63, 64);
    int k = DR[rr] + 16*l;
    float px = 0.5f*(z.x + zm.x), py = 0.5f*(z.y - zm.y);
    float tx = 0.5f*(z.y + zm.y), ty = -0.5f*(z.x - zm.x);
    float ppk = px*px + py*py, ttk = tx*tx + ty*ty;
    float rp = rsqrtf(fmaxf(ppk, 1e-30f)), rt = rsqrtf(fmaxf(ttk, 1e-30f));
    magp += 0.5f*fabsf(ppk*rp - ttk*rt);
    cosp += 0.5f*((px*tx + py*ty)*rp*rt);
    int kk = (k <= 512) ? k : 1024 - k;
    pt[SW(kk)] = make_float2(ppk, ttk);
  }
  if (l <= 32){                    // k = 16*l, weight 1
    float2 z  = spec0[l];
    float2 zm = spec0[(64 - l) & 63];
    float px = 0.5f*(z.x + zm.x), py = 0.5f*(z.y - zm.y);
    float tx = 0.5f*(z.y + zm.y), ty = -0.5f*(z.x - zm.x);
    float ppk = px*px + py*py, ttk = tx*tx + ty*ty;
    float rp = rsqrtf(fmaxf(ppk, 1e-30f)), rt = rsqrtf(fmaxf(ttk, 1e-30f));
    magp += fabsf(ppk*rp - ttk*rt);
    cosp += (px*tx + py*ty)*rp*rt;
    pt[SW(16*l)] = make_float2(ppk, ttk);
  }
  float melp = 0.f;
  const float C = (2595.0f * log10f(1.0f + 8000.0f/700.0f))
                  * (1.0f/81.0f) * (1.0f/2595.0f) * 2.302585093f;
  const float df = 15.625f;
  {
    int m = l;                       // P0: mel m = lane
    float f0 = 700.0f*(__expf(C*(float)(m  )) - 1.0f);
    float f1 = 700.0f*(__expf(C*(float)(m+1)) - 1.0f);
    float f2 = 700.0f*(__expf(C*(float)(m+2)) - 1.0f);
    float i1 = 1.0f/(f1 - f0), i2 = 1.0f/(f2 - f1);
    int lo = (int)ceilf(f0 * (1.0f/df));  if (lo < 0) lo = 0;
    int hi = (int)floorf(f2 * (1.0f/df)); if (hi > 512) hi = 512;
    float pm = 0.f, tm = 0.f;
#pragma unroll 2
    for (int k = lo; k <= hi; ++k){
      float frq = df*(float)k;
      float c = fmaxf(fminf((frq - f0)*i1, (f2 - frq)*i2), 0.f);
      float2 w = pt[SW(k)];
      pm += c*w.x; tm += c*w.y;
    }
    melp += fabsf(__logf(pm + 1e-8f) - __logf(tm + 1e-8f));
  }
  {
    int m = 64 + (l >> 2), q = l & 3;  // P1: 4 lanes per wide mel
    float f0 = 700.0f*(__expf(C*(float)(m  )) - 1.0f);
    float f1 = 700.0f*(__expf(C*(float)(m+1)) - 1.0f);
    float f2 = 700.0f*(__expf(C*(float)(m+2)) - 1.0f);
    float i1 = 1.0f/(f1 - f0), i2 = 1.0f/(f2 - f1);
    int lo = (int)ceilf(f0 * (1.0f/df));  if (lo < 0) lo = 0;
    int hi = (int)floorf(f2 * (1.0f/df)); if (hi > 512) hi = 512;
    int n = hi - lo + 1;
    int ch = (n + 3) >> 2;
    int k0 = lo + q*ch;
    int k1 = k0 + ch; if (k1 > hi + 1) k1 = hi + 1;
    float pm = 0.f, tm = 0.f;
#pragma unroll 2
    for (int k = k0; k < k1; ++k){
      float frq = df*(float)k;
      float c = fmaxf(fminf((frq - f0)*i1, (f2 - frq)*i2), 0.f);
      float2 w = pt[SW(k)];
      pm += c*w.x; tm += c*w.y;
    }
    pm += __shfl_xor(pm, 1, 64); pm += __shfl_xor(pm, 2, 64);
    tm += __shfl_xor(tm, 1, 64); tm += __shfl_xor(tm, 2, 64);
    if (q == 0)
      melp += fabsf(__logf(pm + 1e-8f) - __logf(tm + 1e-8f));
  }
  magp = wred(magp); cosp = wred(cosp); melp = wred(melp);
  if (l == 0){
    int bank = blockIdx.x & 63;
    atomAddD(&g_part[bank][7], (double)magp);
    atomAddD(&g_part[bank][8], (double)cosp);
    atomAddD(&g_part[bank][9], (double)melp);
  }
}

// ---------------- consistency: four-step FFT of 131072 = 128 x 1024 ---------
// n = n1 + 128*n2 ; storage: buf[s*128 + n1], s = rr*64 + l holds spectral
// line K = DR[rr] + 16*l  (natural lane order after the LDS 1024-FFT).
// fwd1: 4-wave blocks (4 n1 each) -> 512 blocks/launch = 2 blocks/CU so two
// blocks hide each other's latency. LDS pool 24 KB, phases aliased:
// input [500][6]x2 (24 KB) -> scr 4x4KB (16 KB) -> LT [4][513] f2 (16.4 KB).
extern "C" __global__ void __launch_bounds__(256) k_fwd1(
    const float* __restrict__ pd, const float* __restrict__ pr,
    float2* __restrict__ buf, int row0){
  __shared__ float SM[6144];                     // 24 KB
  float* LA = SM;                                // [500][6] floats (a)
  float* LB = SM + 3000;                         // [500][6] floats (b)
  float2* LT = (float2*)SM;                      // [4][513] float2 (chunks)
  int wid = threadIdx.x >> 6, l = threadIdx.x & 63;
  int tid = threadIdx.x;
  float2* scr = (float2*)SM + (size_t)wid*512;   // per-wave 4KB fft scratch
  int rl = blockIdx.y;
  int n1base = blockIdx.x * 4;
  int n1 = n1base + wid;
  const float* a = pd + (size_t)(row0+rl)*TLEN;
  const float* b = pr + (size_t)(row0+rl)*TLEN;
  for (int i = tid; i < 1000; i += 256){
    int n2 = i >> 1, wp = (i & 1)*2;
    float2 va = *(const float2*)&a[n1base + wp + 128*n2];
    float2 vb = *(const float2*)&b[n1base + wp + 128*n2];
    *(float2*)&LA[n2*6 + wp] = va;
    *(float2*)&LB[n2*6 + wp] = vb;
  }
  __syncthreads();
  float2 v[16];
#pragma unroll
  for (int m = 0; m < 16; ++m){
    int n2 = l + 64*m;
    if (n2 < 500) v[m] = make_float2(LA[n2*6 + wid], LB[n2*6 + wid]);
    else          v[m] = make_float2(0.f, 0.f);
  }
  __syncthreads();                                // LA/LB reads done (scr aliases)
  fft1024_lds<-1>(v, l, scr);
  const float tw = -(PI2F / (float)NFB);
#pragma unroll
  for (int rr = 0; rr < 16; ++rr){
    int K = DR[rr] + 16*l;
    float ang = tw * (float)(n1*K);               // n1*K < 2^24: exact
    float sn, cs; __sincosf(ang, &sn, &cs);
    v[rr] = cmul(v[rr], make_float2(cs, sn));
  }
  float2* rowp = buf + (size_t)rl*NFB;
  __syncthreads();                                // all waves done with scr
#pragma unroll
  for (int c = 0; c < 2; ++c){
#pragma unroll
    for (int rrl = 0; rrl < 8; ++rrl)
      LT[wid*513 + rrl*64 + l] = v[c*8 + rrl];
    __syncthreads();
#pragma unroll
    for (int it = 0; it < 4; ++it){
      int idx = tid + it*256;                     // 1024 float4s per chunk
      int s = idx >> 1, nw = (idx & 1)*2;         // s in [0,512), nw in {0,2}
      float2 x = LT[nw*513 + s], y = LT[(nw+1)*513 + s];
      *(float4*)&rowp[(size_t)(c*512 + s)*128 + n1base + nw] =
          make_float4(x.x, x.y, y.x, y.y);
    }
    __syncthreads();
  }
}

// D/R split + product for one element (z) given its mirror partner (zm)
__device__ inline float2 pointmul(float2 z, float2 zm){
  float Dx = 0.5f*(z.x + zm.x), Dy = 0.5f*(z.y - zm.y);
  float Rx = 0.5f*(z.y + zm.y), Ry = -0.5f*(z.x - zm.x);
  return make_float2(Dx*Rx - Dy*Ry, Dx*Ry + Dy*Rx);
}

// k_mid: fused fwd2 + pointwise + inv1. One wave per conjugate row pair.
// storage decode for natural-order fwd1: s = dr4(K&15)*64 + (K>>4).
// conj trick: post-pointwise rows satisfy rB[n1] = conj(rA[n1]) exactly.
extern "C" __global__ void __launch_bounds__(256) k_mid(float2* __restrict__ buf){
  int wid = threadIdx.x >> 6, l = threadIdx.x & 63;
  int p = blockIdx.x*4 + wid;           // pair id = K of row A, 0..512
  if (p > 512) return;
  int k2A = p, k2B = (1024 - p) & 1023;
  int sA = dr4(k2A & 15)*64 + (k2A >> 4);
  int sB = dr4(k2B & 15)*64 + (k2B >> 4);
  float2* base = buf + (size_t)blockIdx.y*NFB;
  float2* rA = base + (size_t)sA*128;
  float2* rB = base + (size_t)sB*128;
  bool pair = (sB != sA);
  float2 vA[2] = { rA[l], rA[l+64] };
  float2 vB[2];
  if (pair){ vB[0] = rB[l]; vB[1] = rB[l+64]; }
  fft128_wave<-1>(vA, l);
  if (pair) fft128_wave<-1>(vB, l);
  float2 cA[2];
  if (p == 0){
    int kb = brev6(l);
    int q0 = brev6((64 - kb) & 63);
    float2 zm0 = { __shfl(vA[0].x, q0, 64), __shfl(vA[0].y, q0, 64) };
    float2 zm1 = { __shfl_xor(vA[1].x, 63, 64), __shfl_xor(vA[1].y, 63, 64) };
    cA[0] = pointmul(vA[0], zm0);
    cA[1] = pointmul(vA[1], zm1);
  } else {
    const float2* src = pair ? vB : vA;   // p==512 self-pairs within its own row
    float2 zm0 = { __shfl_xor(src[1].x, 63, 64), __shfl_xor(src[1].y, 63, 64) };
    float2 zm1 = { __shfl_xor(src[0].x, 63, 64), __shfl_xor(src[0].y, 63, 64) };
    cA[0] = pointmul(vA[0], zm0);
    cA[1] = pointmul(vA[1], zm1);
  }
  const float twi = PI2F / (float)NFB;
  ifft128_wave(cA, l);
#pragma unroll
  for (int rr = 0; rr < 2; ++rr){
    int n1 = l + 64*rr;
    float ang = twi * (float)(n1*k2A);
    float sn, cs; __sincosf(ang, &sn, &cs);
    float2 val = cmul(cA[rr], make_float2(cs, sn));
    rA[n1] = val;
    if (pair) rB[n1] = make_float2(val.x, -val.y);   // rB = conj(rA), exact
  }
}

// inv2: column-PAIRED adjoint inverse 1024-pt FFTs; 2-wave blocks (4 cols =
// 2 pairs) -> 512 blocks/launch = 2 blocks/CU. Z = colA + i*colB packed at
// the float4 stage. LDS 20.2 KB: LT [2][513] f2 (scr aliases), LM [500][6].
extern "C" __global__ void __launch_bounds__(128) k_inv2(
    const float* __restrict__ mix, float2* __restrict__ buf, int row0){
  __shared__ float SM[5052];                     // 20.2 KB, aliased phases
  float2* LT = (float2*)SM;                      // [2][513] f2, packed Z
  float* LM = SM + 2052;                         // [500][6] floats (mix)
  int wid = threadIdx.x >> 6, l = threadIdx.x & 63;
  int tid = threadIdx.x;
  float2* scr = (float2*)SM + (size_t)wid*512;   // per-wave 4KB fft scratch
  int rl = blockIdx.y;
  int n1base = blockIdx.x * 4;
  float2* rowp = buf + (size_t)rl*NFB;
  float2 v[16];
#pragma unroll
  for (int c = 0; c < 2; ++c){
#pragma unroll
    for (int it = 0; it < 8; ++it){
      int idx = tid + it*128;                     // 1024 float4s per chunk
      int s = idx >> 1, nw = (idx & 1)*2;         // s in [0,512), nw in {0,2}
      float4 q = *(const float4*)&rowp[(size_t)(c*512 + s)*128 + n1base + nw];
      // Z = colA + i*colB = (x - w, y + z)
      LT[(nw >> 1)*513 + s] = make_float2(q.x - q.w, q.y + q.z);
    }
    __syncthreads();
#pragma unroll
    for (int rrl = 0; rrl < 8; ++rrl)
      v[c*8 + rrl] = LT[wid*513 + rrl*64 + l];
    __syncthreads();                              // LT reads done before reuse
  }
  const float* mr = mix + (size_t)(row0+rl)*TLEN;
  for (int i = tid; i < 1000; i += 128){
    int n2 = i >> 1, wp = (i & 1)*2;
    *(float2*)&LM[n2*6 + wp] = *(const float2*)&mr[n1base + wp + 128*n2];
  }
  ifft1024_lds(v, l, scr);
  __syncthreads();                                // LM ready
  const float invn = 1.0f/(float)NFB;
  float acc = 0.f;
#pragma unroll
  for (int m = 0; m < 16; ++m){
    int n2 = l + 64*m;
    if (n2 < 500){
      float2 mm = *(const float2*)&LM[n2*6 + 2*wid];
      acc += fabsf(v[m].x*invn - mm.x) + fabsf(v[m].y*invn - mm.y);
    }
  }
  acc = wred(acc);
  if (l == 0){
    int bank = (blockIdx.x*2 + wid + blockIdx.y*16) & 63;
    atomAddD(&g_part[bank][10], (double)acc);
  }
}

// ---------------- combine ----------------
extern "C" __global__ void __launch_bounds__(64) k_finalize(float* __restrict__ out){
  __shared__ double s[12];
  int t = threadIdx.x;
  if (t < 12){
    double v = 0.0;
    for (int b = 0; b < 64; ++b) v += g_part[b][t];
    s[t] = v;
  }
  __syncthreads();
  if (t == 0){
    double dt = s[0] / 4096000.0;
    double rt = s[1] / 4096000.0;
    double sp = s[2] / 4096000.0;
    double e0 = s[3] / 1024000.0, e1 = s[4] / 1024000.0;
    double e2 = s[5] / 1024000.0, e3 = s[6] / 1024000.0;
    double dec = fmax(e1 - 0.8*e0, 0.0) + fmax(e2 - 0.8*e1, 0.0) + fmax(e3 - 0.8*e2, 0.0);
    double c1 = 8240832.0;              // 64*513*251
    double freq = s[7]/c1 + 0.1*(1.0 - s[8]/c1);
    double mel  = s[9] / 1285120.0;     // 64*80*251
    double cons = s[10] / 4096000.0;
    double total = 3.0*(dt + 0.5*freq + 0.3*mel)
                 + (rt + 0.1*(sp + dec))
                 + 0.2*cons;
    out[0] = (float)total;
  }
}

extern "C" void kernel_launch(void* const* d_in, const int* in_sizes, int n_in,
                              void* d_out, int out_size, void* d_ws, size_t ws_size,
                              hipStream_t stream){
  const float* pd = (const float*)d_in[0];
  const float* pr = (const float*)d_in[1];
  const float* td = (const float*)d_in[2];
  const float* tr = (const float*)d_in[3];
  const float* mx = (const float*)d_in[4];
  float* out = (float*)d_out;
  float2* buf = (float2*)d_ws;

  size_t rowBytes = (size_t)NFB * sizeof(float2);     // 1 MiB per row
  int maxrows = (int)(ws_size / rowBytes);
  if (maxrows > ROWS) maxrows = ROWS;
  if (maxrows < 1) maxrows = 1;
  // grid-balanced chunking: chrows divides 64 so every chunk is equal
  int chrows = 1;
  const int cand[7] = {64, 32, 16, 8, 4, 2, 1};
  for (int i = 0; i < 7; ++i) if (cand[i] <= maxrows){ chrows = cand[i]; break; }

  hipLaunchKernelGGL(k_init, dim3(3), dim3(256), 0, stream);
  hipLaunchKernelGGL(k_time, dim3(2048), dim3(256), 0, stream, pd, td, pr, tr);
  hipLaunchKernelGGL(k_stft, dim3(ROWS*NFR), dim3(64), 0, stream, pd, td);
  for (int row0 = 0; row0 < ROWS; row0 += chrows){
    int nr = ROWS - row0; if (nr > chrows) nr = chrows;
    hipLaunchKernelGGL(k_fwd1, dim3(32, nr),  dim3(256), 0, stream, pd, pr, buf, row0);
    hipLaunchKernelGGL(k_mid,  dim3(129, nr), dim3(256), 0, stream, buf);
    hipLaunchKernelGGL(k_inv2, dim3(32, nr),  dim3(128), 0, stream, mx, buf, row0);
  }
  hipLaunchKernelGGL(k_finalize, dim3(1), dim3(64), 0, stream, out);
}

// Round 7
// 254.523 us; speedup vs baseline: 1.3219x; 1.3219x over previous
//
#include <hip/hip_runtime.h>
#include <math.h>

#define ROWS 64
#define TLEN 64000
#define NFR 251
#define NMELS 80
#define NFB 131072            // big FFT length (>= 2*T-1 -> exact linear conv)
#define PI2F 6.28318530717958647692f
#define PI_F 3.14159265358979323846f

// banked double accumulators:
// 0 S_dt  1 S_rt  2 S_sp  3..6 E0..E3  7 S_mag  8 S_cos  9 S_mel  10 S_c
__device__ double g_part[64][12];

// slot holding k2 after per-lane radix-4 FFT16 (digit reversal, involution)
__device__ constexpr int DR[16] = {0,4,8,12,1,5,9,13,2,6,10,14,3,7,11,15};
// mirror slot: RM[r] = DR[16 - DR[r]]
__device__ constexpr int RM[16] = {0,3,2,1,15,14,13,12,11,10,9,8,7,6,5,4};

__device__ inline int dr4(int i){ return ((i & 3) << 2) | (i >> 2); }  // DR, runtime
// bank-conflict-free swizzle for stride-16 writes into 513-entry arrays
__device__ inline int SW(int k){ return k + (k >> 5); }

__device__ inline void atomAddD(double* p, double v){
  __hip_atomic_fetch_add(p, v, __ATOMIC_RELAXED, __HIP_MEMORY_SCOPE_AGENT);
}
__device__ inline int brev6(int x){ return (int)((unsigned)__brev((unsigned)x) >> 26); }
__device__ inline float2 cmul(float2 a, float2 b){
  return make_float2(a.x*b.x - a.y*b.y, a.x*b.y + a.y*b.x);
}
__device__ inline float wred(float v){
#pragma unroll
  for (int o = 32; o > 0; o >>= 1) v += __shfl_down(v, o, 64);
  return v;
}

// wave-local LDS fence: DS traffic inside fft64_lds is per-wave cross-lane ->
// only this wave's lgkmcnt needs draining, NOT a workgroup barrier.
__device__ inline void wave_fence(){
  asm volatile("s_waitcnt lgkmcnt(0)" ::: "memory");
}

// ---------- shuffle cross-lane FFT (kept only for the 128-pt path in k_mid) ----------
template<int S, int N>
__device__ inline void fft64_lanes(float2* v, int l){
  float2 W[5];
#pragma unroll
  for (int si = 0; si < 5; ++si){
    int d = 32 >> si;
    float a = (float)S * PI_F * (float)(l & (d-1)) * (1.0f/(float)d);
    float sn, cs; __sincosf(a, &sn, &cs);
    W[si] = make_float2(cs, sn);
  }
#pragma unroll
  for (int si = 0; si < 6; ++si){
    int d = 32 >> si;
    bool hi = (l & d) != 0;
#pragma unroll
    for (int rr = 0; rr < N; ++rr){
      float2 x = v[rr];
      float tx = __shfl_xor(x.x, d, 64);
      float ty = __shfl_xor(x.y, d, 64);
      float sx = x.x + tx, sy = x.y + ty;
      float dx = tx - x.x, dy = ty - x.y;
      float rx, ry;
      if (si < 5){ rx = dx*W[si].x - dy*W[si].y; ry = dx*W[si].y + dy*W[si].x; }
      else       { rx = dx; ry = dy; }
      v[rr].x = hi ? rx : sx;
      v[rr].y = hi ? ry : sy;
    }
  }
}

template<int S>
__device__ inline void fft16_reg(float2* v){
  const float Sf = (float)S;
  const float C1 = 0.9238795325112867f, S1 = 0.3826834323650898f, C2 = 0.7071067811865476f;
  const float2 W1[4] = {{1.f,0.f},{C1,Sf*S1},{C2,Sf*C2},{S1,Sf*C1}};
  const float2 W2[4] = {{1.f,0.f},{C2,Sf*C2},{0.f,Sf},{-C2,Sf*C2}};
  const float2 W3[4] = {{1.f,0.f},{S1,Sf*C1},{-C2,Sf*C2},{-C1,-Sf*S1}};
#pragma unroll
  for (int j = 0; j < 4; ++j){
    float2 x0=v[j], x1=v[j+4], x2=v[j+8], x3=v[j+12];
    float2 t0={x0.x+x2.x, x0.y+x2.y}, t1={x0.x-x2.x, x0.y-x2.y};
    float2 t2={x1.x+x3.x, x1.y+x3.y}, t3={x1.x-x3.x, x1.y-x3.y};
    float2 y0={t0.x+t2.x, t0.y+t2.y};
    float2 y2={t0.x-t2.x, t0.y-t2.y};
    float2 y1={t1.x - Sf*t3.y, t1.y + Sf*t3.x};
    float2 y3={t1.x + Sf*t3.y, t1.y - Sf*t3.x};
    v[j]=y0; v[j+4]=cmul(y1,W1[j]); v[j+8]=cmul(y2,W2[j]); v[j+12]=cmul(y3,W3[j]);
  }
#pragma unroll
  for (int b = 0; b < 4; ++b){
    float2 x0=v[4*b], x1=v[4*b+1], x2=v[4*b+2], x3=v[4*b+3];
    float2 t0={x0.x+x2.x, x0.y+x2.y}, t1={x0.x-x2.x, x0.y-x2.y};
    float2 t2={x1.x+x3.x, x1.y+x3.y}, t3={x1.x-x3.x, x1.y-x3.y};
    v[4*b]   = make_float2(t0.x+t2.x, t0.y+t2.y);
    v[4*b+2] = make_float2(t0.x-t2.x, t0.y-t2.y);
    v[4*b+1] = make_float2(t1.x - Sf*t3.y, t1.y + Sf*t3.x);
    v[4*b+3] = make_float2(t1.x + Sf*t3.y, t1.y - Sf*t3.x);
  }
}

// 128-pt forward: input v[m]=x[l+64m]; output slot rr, lane l = X[rr+2*brev6(l)]
template<int S>
__device__ inline void fft128_wave(float2* v, int l){
  float2 a = {v[0].x+v[1].x, v[0].y+v[1].y};
  float2 b = {v[0].x-v[1].x, v[0].y-v[1].y};
  float ang = (float)S * PI_F * (float)l * (1.0f/64.0f);
  float sn, cs; __sincosf(ang, &sn, &cs);
  v[0] = a; v[1] = cmul(b, make_float2(cs, sn));
  fft64_lanes<S,2>(v, l);
}

// ---------- LDS-based cross-lane 64-FFT (four-step 8x8), natural in/out ----------
template<int S>
__device__ inline void fft8p(float2* y){
  const float Sf = (float)S;
  const float C2 = 0.7071067811865476f;
  float2 t0={y[0].x+y[4].x, y[0].y+y[4].y};
  float2 t1={y[1].x+y[5].x, y[1].y+y[5].y};
  float2 t2={y[2].x+y[6].x, y[2].y+y[6].y};
  float2 t3={y[3].x+y[7].x, y[3].y+y[7].y};
  float2 u0={y[0].x-y[4].x, y[0].y-y[4].y};
  float2 u1={y[1].x-y[5].x, y[1].y-y[5].y};
  float2 u2={y[2].x-y[6].x, y[2].y-y[6].y};
  float2 u3={y[3].x-y[7].x, y[3].y-y[7].y};
  { float x=u1.x, yy=u1.y; u1.x = C2*(x - Sf*yy); u1.y = C2*(Sf*x + yy); }
  { float x=u2.x, yy=u2.y; u2.x = -Sf*yy;         u2.y = Sf*x; }
  { float x=u3.x, yy=u3.y; u3.x = -C2*(x + Sf*yy); u3.y = C2*(Sf*x - yy); }
  {
    float2 e0={t0.x+t2.x,t0.y+t2.y}, e1={t0.x-t2.x,t0.y-t2.y};
    float2 o0={t1.x+t3.x,t1.y+t3.y}, o1={t1.x-t3.x,t1.y-t3.y};
    y[0]=make_float2(e0.x+o0.x, e0.y+o0.y);
    y[4]=make_float2(e0.x-o0.x, e0.y-o0.y);
    y[2]=make_float2(e1.x - Sf*o1.y, e1.y + Sf*o1.x);
    y[6]=make_float2(e1.x + Sf*o1.y, e1.y - Sf*o1.x);
  }
  {
    float2 e0={u0.x+u2.x,u0.y+u2.y}, e1={u0.x-u2.x,u0.y-u2.y};
    float2 o0={u1.x+u3.x,u1.y+u3.y}, o1={u1.x-u3.x,u1.y-u3.y};
    y[1]=make_float2(e0.x+o0.x, e0.y+o0.y);
    y[5]=make_float2(e0.x-o0.x, e0.y-o0.y);
    y[3]=make_float2(e1.x - Sf*o1.y, e1.y + Sf*o1.x);
    y[7]=make_float2(e1.x + Sf*o1.y, e1.y - Sf*o1.x);
  }
}

// 16 independent 64-pt FFTs across lanes, natural order, per-wave 4KB scratch.
template<int S>
__device__ inline void fft64_lds(float2* v, int l, float2* scr){
  int s = l >> 3, a = l & 7;
  int sw = (s & 1);
#pragma unroll
  for (int h = 0; h < 2; ++h){
    float2* vh = v + 8*h;
#pragma unroll
    for (int r = 0; r < 8; ++r) scr[r*64 + l] = vh[r];
    wave_fence();
    float2 y[8];
#pragma unroll
    for (int j = 0; j < 8; ++j)
      y[j] = scr[s*64 + a + 8*((j + s) & 7)];
    fft8p<S>(y);
    {
      float ang = (float)S * PI2F * (float)l * (1.0f/64.0f);
      float sn, cs; __sincosf(ang, &sn, &cs);
      float2 b1 = make_float2(cs, sn), cur = b1;
#pragma unroll
      for (int c = 1; c < 8; ++c){
        y[c] = cmul(y[c], cur);
        if (c < 7) cur = cmul(cur, b1);
      }
    }
    wave_fence();
#pragma unroll
    for (int c = 0; c < 8; ++c)
      scr[s*64 + a + 8*(c ^ sw)] = y[c];
    wave_fence();
    float2 z[8];
#pragma unroll
    for (int j = 0; j < 8; ++j)
      z[j] = scr[s*64 + ((j + s) & 7) + 8*(a ^ sw)];
    fft8p<S>(z);
    {
      float ang2 = (float)S * PI2F * (float)s * 0.125f;
      float sn2, cs2; __sincosf(ang2, &sn2, &cs2);
      float2 b2 = make_float2(cs2, sn2), cur = b2;
#pragma unroll
      for (int d = 1; d < 8; ++d){
        z[d] = cmul(z[d], cur);
        if (d < 7) cur = cmul(cur, b2);
      }
    }
    wave_fence();
#pragma unroll
    for (int d = 0; d < 8; ++d)
      scr[s*64 + a + 8*(d ^ sw)] = z[d];
    wave_fence();
#pragma unroll
    for (int r = 0; r < 8; ++r)
      vh[r] = scr[r*64 + (l ^ ((r & 1) << 3))];
    wave_fence();
  }
}

// 1024-pt forward via LDS: input v[m]=x[l+64m]; output slot rr, lane l =
// X[DR[rr] + 16*l]   (NATURAL lane order)
template<int S>
__device__ inline void fft1024_lds(float2* v, int l, float2* scr){
  fft16_reg<S>(v);
  float a = (float)S * PI2F * (float)l * (1.0f/1024.0f);
  float sn, cs; __sincosf(a, &sn, &cs);
  float2 T = make_float2(cs, sn);
  float2 cur = T;
#pragma unroll
  for (int k2 = 1; k2 < 16; ++k2){
    v[DR[k2]] = cmul(v[DR[k2]], cur);
    if (k2 < 15) cur = cmul(cur, T);
  }
  fft64_lds<S>(v, l, scr);
}

__device__ inline void r4p(float2* v, int i0, int i1, int i2, int i3){
  float2 x0=v[i0], x1=v[i1], x2=v[i2], x3=v[i3];
  float2 t0={x0.x+x2.x, x0.y+x2.y}, t1={x0.x-x2.x, x0.y-x2.y};
  float2 t2={x1.x+x3.x, x1.y+x3.y}, t3={x1.x-x3.x, x1.y-x3.y};
  v[i0] = make_float2(t0.x+t2.x, t0.y+t2.y);
  v[i2] = make_float2(t0.x-t2.x, t0.y-t2.y);
  v[i1] = make_float2(t1.x - t3.y, t1.y + t3.x);
  v[i3] = make_float2(t1.x + t3.y, t1.y - t3.x);
}

__device__ inline void ifft16_reg(float2* v){
#pragma unroll
  for (int b = 0; b < 4; ++b) r4p(v, 4*b, 4*b+1, 4*b+2, 4*b+3);
  const float C1 = 0.9238795325112867f, S1 = 0.3826834323650898f, C2 = 0.7071067811865476f;
  const float2 W1[4] = {{1.f,0.f},{C1,S1},{C2,C2},{S1,C1}};
  const float2 W2[4] = {{1.f,0.f},{C2,C2},{0.f,1.f},{-C2,C2}};
  const float2 W3[4] = {{1.f,0.f},{S1,C1},{-C2,C2},{-C1,-S1}};
#pragma unroll
  for (int j = 1; j < 4; ++j){
    v[j+4]  = cmul(v[j+4],  W1[j]);
    v[j+8]  = cmul(v[j+8],  W2[j]);
    v[j+12] = cmul(v[j+12], W3[j]);
  }
#pragma unroll
  for (int j = 0; j < 4; ++j) r4p(v, j, j+4, j+8, j+12);
}

__device__ inline void ifft1024_lds(float2* v, int l, float2* scr){
  fft64_lds<1>(v, l, scr);            // inverse 64-FFT over lanes, natural order
  float a = PI2F * (float)l * (1.0f/1024.0f);
  float sn, cs; __sincosf(a, &sn, &cs);
  float2 T = make_float2(cs, sn);
  float2 cur = T;
#pragma unroll
  for (int k2 = 1; k2 < 16; ++k2){
    v[DR[k2]] = cmul(v[DR[k2]], cur);
    if (k2 < 15) cur = cmul(cur, T);
  }
  ifft16_reg(v);
}

// ---------- adjoint inverse 64 over lanes (shuffle, for k_mid's 128 path) ----------
template<int N>
__device__ inline void ifft64_lanes(float2* v, int l){
  float2 W[5];
#pragma unroll
  for (int si = 0; si < 5; ++si){
    int d = 32 >> si;
    float a = PI_F * (float)(l & (d-1)) * (1.0f/(float)d);   // conj of forward
    float sn, cs; __sincosf(a, &sn, &cs);
    W[si] = make_float2(cs, sn);
  }
#pragma unroll
  for (int si = 5; si >= 0; --si){
    int d = 32 >> si;
    bool hi = (l & d) != 0;
#pragma unroll
    for (int rr = 0; rr < N; ++rr){
      float2 x = v[rr];
      float2 xp = x;
      if (si < 5 && hi) xp = cmul(x, W[si]);
      float tx = __shfl_xor(xp.x, d, 64);
      float ty = __shfl_xor(xp.y, d, 64);
      v[rr].x = hi ? (tx - xp.x) : (xp.x + tx);
      v[rr].y = hi ? (ty - xp.y) : (xp.y + ty);
    }
  }
}

// input slot rr, lane l = X[rr+2*brev6(l)]; output v[m], lane l = 128*x[l+64m]
__device__ inline void ifft128_wave(float2* v, int l){
  ifft64_lanes<2>(v, l);
  float ang = PI_F * (float)l * (1.0f/64.0f);
  float sn, cs; __sincosf(ang, &sn, &cs);
  v[1] = cmul(v[1], make_float2(cs, sn));
  float2 a = {v[0].x+v[1].x, v[0].y+v[1].y};
  float2 b = {v[0].x-v[1].x, v[0].y-v[1].y};
  v[0] = a; v[1] = b;
}

// ---------------- init: zero accumulators ----------------
extern "C" __global__ void __launch_bounds__(256) k_init(){
  int t = blockIdx.x*256 + threadIdx.x;
  if (t < 768) ((double*)g_part)[t] = 0.0;
}

// ---------------- time-domain losses + rir segment energies (float4) -------
extern "C" __global__ void __launch_bounds__(256) k_time(
    const float* __restrict__ pd, const float* __restrict__ td,
    const float* __restrict__ pr, const float* __restrict__ tr){
  const int N4 = ROWS*TLEN/4;          // 1,024,000 float4s; 16000 per row
  int stride = gridDim.x * 256;
  float sdt=0.f, srt=0.f, ssp=0.f, e0=0.f, e1=0.f, e2=0.f, e3=0.f;
  const float4* pd4 = (const float4*)pd;
  const float4* td4 = (const float4*)td;
  const float4* pr4 = (const float4*)pr;
  const float4* tr4 = (const float4*)tr;
  for (int i = blockIdx.x*256 + threadIdx.x; i < N4; i += stride){
    float4 a = pd4[i], b = td4[i], p = pr4[i], q = tr4[i];
    sdt += fabsf(a.x-b.x)+fabsf(a.y-b.y)+fabsf(a.z-b.z)+fabsf(a.w-b.w);
    srt += fabsf(p.x-q.x)+fabsf(p.y-q.y)+fabsf(p.z-q.z)+fabsf(p.w-q.w);
    ssp += fabsf(p.x)+fabsf(p.y)+fabsf(p.z)+fabsf(p.w);
    float p2 = p.x*p.x + p.y*p.y + p.z*p.z + p.w*p.w;
    int seg = (i % 16000) / 4000;      // uniform for all 4 elems
    if (seg == 0) e0 += p2; else if (seg == 1) e1 += p2;
    else if (seg == 2) e2 += p2; else e3 += p2;
  }
  sdt = wred(sdt); srt = wred(srt); ssp = wred(ssp);
  e0 = wred(e0); e1 = wred(e1); e2 = wred(e2); e3 = wred(e3);
  if ((threadIdx.x & 63) == 0){
    int bank = (blockIdx.x*4 + (threadIdx.x >> 6)) & 63;
    atomAddD(&g_part[bank][0], (double)sdt);
    atomAddD(&g_part[bank][1], (double)srt);
    atomAddD(&g_part[bank][2], (double)ssp);
    atomAddD(&g_part[bank][3], (double)e0);
    atomAddD(&g_part[bank][4], (double)e1);
    atomAddD(&g_part[bank][5], (double)e2);
    atomAddD(&g_part[bank][6], (double)e3);
  }
}

// ---------------- fused STFT (freq + mel) losses, ONE WAVE PER BLOCK --------
extern "C" __global__ void __launch_bounds__(64) k_stft(
    const float* __restrict__ pd, const float* __restrict__ td){
  __shared__ float2 scr[512];             // 4KB four-step scratch
  __shared__ float2 spec0[64];
  __shared__ float2 pt[530];              // (pp,tt) pairs, swizzled SW(k)=k+(k>>5)
  int l = threadIdx.x;
  // XCD-aware swizzle: 16064 = 8*2008 exactly; consecutive frames on same XCD
  int frame = (blockIdx.x & 7) * (ROWS*NFR/8) + (blockIdx.x >> 3);
  int r = frame / NFR, fr = frame - r*NFR;
  const float* pdr = pd + (size_t)r*TLEN;
  const float* tdr = td + (size_t)r*TLEN;
  const float scale = 0.05103103630798288f;   // 1/sqrt(384), folded into window
  int base = fr*256 - 512;
  float2 v[16];
#pragma unroll
  for (int m = 0; m < 16; ++m){
    int j = l + 64*m;
    int g = base + j;
    g = (g < 0) ? -g : ((g >= TLEN) ? (2*TLEN - 2 - g) : g);
    float w = (0.5f - 0.5f*__cosf((PI2F/1024.0f)*(float)j)) * scale;
    v[m] = make_float2(pdr[g]*w, tdr[g]*w);
  }
  fft1024_lds<-1>(v, l, scr);
  // output: slot rr, lane l = X[DR[rr] + 16*l]  (natural lane order)
  spec0[l] = v[0];          // the k2=0 line: Z[16*k1] at index k1
  float magp = 0.f, cosp = 0.f;
  // k2 = 1..15 lines: mirror of (slot rr, lane l) is (slot RM[rr], lane l^63).
#pragma unroll
  for (int rr = 1; rr < 16; ++rr){
    float2 z = v[rr];
    float2 zm;
    zm.x = __shfl_xor(v[RM[rr]].x, 63, 64);
    zm.y = __shfl_xor(v[RM[rr]].y, 63, 64);
    int k = DR[rr] + 16*l;
    float px = 0.5f*(z.x + zm.x), py = 0.5f*(z.y - zm.y);
    float tx = 0.5f*(z.y + zm.y), ty = -0.5f*(z.x - zm.x);
    float ppk = px*px + py*py, ttk = tx*tx + ty*ty;
    float rp = rsqrtf(fmaxf(ppk, 1e-30f)), rt = rsqrtf(fmaxf(ttk, 1e-30f));
    magp += 0.5f*fabsf(ppk*rp - ttk*rt);
    cosp += 0.5f*((px*tx + py*ty)*rp*rt);
    int kk = (k <= 512) ? k : 1024 - k;
    pt[SW(kk)] = make_float2(ppk, ttk);
  }
  if (l <= 32){                    // k = 16*l, weight 1
    float2 z  = spec0[l];
    float2 zm = spec0[(64 - l) & 63];
    float px = 0.5f*(z.x + zm.x), py = 0.5f*(z.y - zm.y);
    float tx = 0.5f*(z.y + zm.y), ty = -0.5f*(z.x - zm.x);
    float ppk = px*px + py*py, ttk = tx*tx + ty*ty;
    float rp = rsqrtf(fmaxf(ppk, 1e-30f)), rt = rsqrtf(fmaxf(ttk, 1e-30f));
    magp += fabsf(ppk*rp - ttk*rt);
    cosp += (px*tx + py*ty)*rp*rt;
    pt[SW(16*l)] = make_float2(ppk, ttk);
  }
  float melp = 0.f;
  const float C = (2595.0f * log10f(1.0f + 8000.0f/700.0f))
                  * (1.0f/81.0f) * (1.0f/2595.0f) * 2.302585093f;
  const float df = 15.625f;
  {
    int m = l;                       // P0: mel m = lane
    float f0 = 700.0f*(__expf(C*(float)(m  )) - 1.0f);
    float f1 = 700.0f*(__expf(C*(float)(m+1)) - 1.0f);
    float f2 = 700.0f*(__expf(C*(float)(m+2)) - 1.0f);
    float i1 = 1.0f/(f1 - f0), i2 = 1.0f/(f2 - f1);
    int lo = (int)ceilf(f0 * (1.0f/df));  if (lo < 0) lo = 0;
    int hi = (int)floorf(f2 * (1.0f/df)); if (hi > 512) hi = 512;
    float pm = 0.f, tm = 0.f;
#pragma unroll 2
    for (int k = lo; k <= hi; ++k){
      float frq = df*(float)k;
      float c = fmaxf(fminf((frq - f0)*i1, (f2 - frq)*i2), 0.f);
      float2 w = pt[SW(k)];
      pm += c*w.x; tm += c*w.y;
    }
    melp += fabsf(__logf(pm + 1e-8f) - __logf(tm + 1e-8f));
  }
  {
    int m = 64 + (l >> 2), q = l & 3;  // P1: 4 lanes per wide mel
    float f0 = 700.0f*(__expf(C*(float)(m  )) - 1.0f);
    float f1 = 700.0f*(__expf(C*(float)(m+1)) - 1.0f);
    float f2 = 700.0f*(__expf(C*(float)(m+2)) - 1.0f);
    float i1 = 1.0f/(f1 - f0), i2 = 1.0f/(f2 - f1);
    int lo = (int)ceilf(f0 * (1.0f/df));  if (lo < 0) lo = 0;
    int hi = (int)floorf(f2 * (1.0f/df)); if (hi > 512) hi = 512;
    int n = hi - lo + 1;
    int ch = (n + 3) >> 2;
    int k0 = lo + q*ch;
    int k1 = k0 + ch; if (k1 > hi + 1) k1 = hi + 1;
    float pm = 0.f, tm = 0.f;
#pragma unroll 2
    for (int k = k0; k < k1; ++k){
      float frq = df*(float)k;
      float c = fmaxf(fminf((frq - f0)*i1, (f2 - frq)*i2), 0.f);
      float2 w = pt[SW(k)];
      pm += c*w.x; tm += c*w.y;
    }
    pm += __shfl_xor(pm, 1, 64); pm += __shfl_xor(pm, 2, 64);
    tm += __shfl_xor(tm, 1, 64); tm += __shfl_xor(tm, 2, 64);
    if (q == 0)
      melp += fabsf(__logf(pm + 1e-8f) - __logf(tm + 1e-8f));
  }
  magp = wred(magp); cosp = wred(cosp); melp = wred(melp);
  if (l == 0){
    int bank = blockIdx.x & 63;
    atomAddD(&g_part[bank][7], (double)magp);
    atomAddD(&g_part[bank][8], (double)cosp);
    atomAddD(&g_part[bank][9], (double)melp);
  }
}

// ---------------- consistency: four-step FFT of 131072 = 128 x 1024 ---------
// n = n1 + 128*n2 ; storage: buf[s*128 + n1], s = rr*64 + l holds spectral
// line K = DR[rr] + 16*l  (natural lane order after the LDS 1024-FFT).
// fwd1: 4-wave blocks (4 n1 each), 1D grid with XCD-locality remap: the 4-8
// blocks sharing each input cacheline (adjacent bx, same row) get consecutive
// in-XCD dispatch slots -> one HBM fetch per line instead of 4 (R6: 128 MB
// fetched vs 33 MB ideal because adjacent blocks round-robin across XCD L2s).
extern "C" __global__ void __launch_bounds__(256) k_fwd1(
    const float* __restrict__ pd, const float* __restrict__ pr,
    float2* __restrict__ buf, int row0){
  __shared__ float SM[6144];                     // 24 KB
  float* LA = SM;                                // [500][6] floats (a)
  float* LB = SM + 3000;                         // [500][6] floats (b)
  float2* LT = (float2*)SM;                      // [4][513] float2 (chunks)
  int wid = threadIdx.x >> 6, l = threadIdx.x & 63;
  int tid = threadIdx.x;
  float2* scr = (float2*)SM + (size_t)wid*512;   // per-wave 4KB fft scratch
  // XCD-locality remap: work w ordered (row-major over rows, then bx);
  // dispatcher sends flat%8 -> XCD, so XCD k runs works [k*cpx,(k+1)*cpx).
  int flat = blockIdx.x;
  int cpx = gridDim.x >> 3;                      // gridDim.x = 32*nr, 8 | 32
  int w = (flat & 7) * cpx + (flat >> 3);
  int rl = w >> 5;
  int n1base = (w & 31) * 4;
  int n1 = n1base + wid;
  const float* a = pd + (size_t)(row0+rl)*TLEN;
  const float* b = pr + (size_t)(row0+rl)*TLEN;
  for (int i = tid; i < 1000; i += 256){
    int n2 = i >> 1, wp = (i & 1)*2;
    float2 va = *(const float2*)&a[n1base + wp + 128*n2];
    float2 vb = *(const float2*)&b[n1base + wp + 128*n2];
    *(float2*)&LA[n2*6 + wp] = va;
    *(float2*)&LB[n2*6 + wp] = vb;
  }
  __syncthreads();
  float2 v[16];
#pragma unroll
  for (int m = 0; m < 16; ++m){
    int n2 = l + 64*m;
    if (n2 < 500) v[m] = make_float2(LA[n2*6 + wid], LB[n2*6 + wid]);
    else          v[m] = make_float2(0.f, 0.f);
  }
  __syncthreads();                                // LA/LB reads done (scr aliases)
  fft1024_lds<-1>(v, l, scr);
  const float tw = -(PI2F / (float)NFB);
#pragma unroll
  for (int rr = 0; rr < 16; ++rr){
    int K = DR[rr] + 16*l;
    float ang = tw * (float)(n1*K);               // n1*K < 2^24: exact
    float sn, cs; __sincosf(ang, &sn, &cs);
    v[rr] = cmul(v[rr], make_float2(cs, sn));
  }
  float2* rowp = buf + (size_t)rl*NFB;
  __syncthreads();                                // all waves done with scr
#pragma unroll
  for (int c = 0; c < 2; ++c){
#pragma unroll
    for (int rrl = 0; rrl < 8; ++rrl)
      LT[wid*513 + rrl*64 + l] = v[c*8 + rrl];
    __syncthreads();
#pragma unroll
    for (int it = 0; it < 4; ++it){
      int idx = tid + it*256;                     // 1024 float4s per chunk
      int s = idx >> 1, nw = (idx & 1)*2;         // s in [0,512), nw in {0,2}
      float2 x = LT[nw*513 + s], y = LT[(nw+1)*513 + s];
      *(float4*)&rowp[(size_t)(c*512 + s)*128 + n1base + nw] =
          make_float4(x.x, x.y, y.x, y.y);
    }
    __syncthreads();
  }
}

// D/R split + product for one element (z) given its mirror partner (zm)
__device__ inline float2 pointmul(float2 z, float2 zm){
  float Dx = 0.5f*(z.x + zm.x), Dy = 0.5f*(z.y - zm.y);
  float Rx = 0.5f*(z.y + zm.y), Ry = -0.5f*(z.x - zm.x);
  return make_float2(Dx*Rx - Dy*Ry, Dx*Ry + Dy*Rx);
}

// k_mid: fused fwd2 + pointwise + inv1. One wave per conjugate row pair.
// storage decode for natural-order fwd1: s = dr4(K&15)*64 + (K>>4).
// conj trick: post-pointwise rows satisfy rB[n1] = conj(rA[n1]) exactly.
extern "C" __global__ void __launch_bounds__(256) k_mid(float2* __restrict__ buf){
  int wid = threadIdx.x >> 6, l = threadIdx.x & 63;
  int p = blockIdx.x*4 + wid;           // pair id = K of row A, 0..512
  if (p > 512) return;
  int k2A = p, k2B = (1024 - p) & 1023;
  int sA = dr4(k2A & 15)*64 + (k2A >> 4);
  int sB = dr4(k2B & 15)*64 + (k2B >> 4);
  float2* base = buf + (size_t)blockIdx.y*NFB;
  float2* rA = base + (size_t)sA*128;
  float2* rB = base + (size_t)sB*128;
  bool pair = (sB != sA);
  float2 vA[2] = { rA[l], rA[l+64] };
  float2 vB[2];
  if (pair){ vB[0] = rB[l]; vB[1] = rB[l+64]; }
  fft128_wave<-1>(vA, l);
  if (pair) fft128_wave<-1>(vB, l);
  float2 cA[2];
  if (p == 0){
    int kb = brev6(l);
    int q0 = brev6((64 - kb) & 63);
    float2 zm0 = { __shfl(vA[0].x, q0, 64), __shfl(vA[0].y, q0, 64) };
    float2 zm1 = { __shfl_xor(vA[1].x, 63, 64), __shfl_xor(vA[1].y, 63, 64) };
    cA[0] = pointmul(vA[0], zm0);
    cA[1] = pointmul(vA[1], zm1);
  } else {
    const float2* src = pair ? vB : vA;   // p==512 self-pairs within its own row
    float2 zm0 = { __shfl_xor(src[1].x, 63, 64), __shfl_xor(src[1].y, 63, 64) };
    float2 zm1 = { __shfl_xor(src[0].x, 63, 64), __shfl_xor(src[0].y, 63, 64) };
    cA[0] = pointmul(vA[0], zm0);
    cA[1] = pointmul(vA[1], zm1);
  }
  const float twi = PI2F / (float)NFB;
  ifft128_wave(cA, l);
#pragma unroll
  for (int rr = 0; rr < 2; ++rr){
    int n1 = l + 64*rr;
    float ang = twi * (float)(n1*k2A);
    float sn, cs; __sincosf(ang, &sn, &cs);
    float2 val = cmul(cA[rr], make_float2(cs, sn));
    rA[n1] = val;
    if (pair) rB[n1] = make_float2(val.x, -val.y);   // rB = conj(rA), exact
  }
}

// inv2: column-PAIRED adjoint inverse 1024-pt FFTs; 2-wave blocks (4 cols =
// 2 pairs). Same XCD-locality remap as fwd1: the 4 blocks sharing each buf
// cacheline run on one XCD's L2 -> ~1x fetch of buf instead of ~4x.
extern "C" __global__ void __launch_bounds__(128) k_inv2(
    const float* __restrict__ mix, float2* __restrict__ buf, int row0){
  __shared__ float SM[5052];                     // 20.2 KB, aliased phases
  float2* LT = (float2*)SM;                      // [2][513] f2, packed Z
  float* LM = SM + 2052;                         // [500][6] floats (mix)
  int wid = threadIdx.x >> 6, l = threadIdx.x & 63;
  int tid = threadIdx.x;
  float2* scr = (float2*)SM + (size_t)wid*512;   // per-wave 4KB fft scratch
  int flat = blockIdx.x;
  int cpx = gridDim.x >> 3;                      // gridDim.x = 32*nr
  int w = (flat & 7) * cpx + (flat >> 3);
  int rl = w >> 5;
  int n1base = (w & 31) * 4;
  float2* rowp = buf + (size_t)rl*NFB;
  float2 v[16];
#pragma unroll
  for (int c = 0; c < 2; ++c){
#pragma unroll
    for (int it = 0; it < 8; ++it){
      int idx = tid + it*128;                     // 1024 float4s per chunk
      int s = idx >> 1, nw = (idx & 1)*2;         // s in [0,512), nw in {0,2}
      float4 q = *(const float4*)&rowp[(size_t)(c*512 + s)*128 + n1base + nw];
      // Z = colA + i*colB = (x - w, y + z)
      LT[(nw >> 1)*513 + s] = make_float2(q.x - q.w, q.y + q.z);
    }
    __syncthreads();
#pragma unroll
    for (int rrl = 0; rrl < 8; ++rrl)
      v[c*8 + rrl] = LT[wid*513 + rrl*64 + l];
    __syncthreads();                              // LT reads done before reuse
  }
  const float* mr = mix + (size_t)(row0+rl)*TLEN;
  for (int i = tid; i < 1000; i += 128){
    int n2 = i >> 1, wp = (i & 1)*2;
    *(float2*)&LM[n2*6 + wp] = *(const float2*)&mr[n1base + wp + 128*n2];
  }
  ifft1024_lds(v, l, scr);
  __syncthreads();                                // LM ready
  const float invn = 1.0f/(float)NFB;
  float acc = 0.f;
#pragma unroll
  for (int m = 0; m < 16; ++m){
    int n2 = l + 64*m;
    if (n2 < 500){
      float2 mm = *(const float2*)&LM[n2*6 + 2*wid];
      acc += fabsf(v[m].x*invn - mm.x) + fabsf(v[m].y*invn - mm.y);
    }
  }
  acc = wred(acc);
  if (l == 0){
    int bank = (flat*2 + wid) & 63;
    atomAddD(&g_part[bank][10], (double)acc);
  }
}

// ---------------- combine ----------------
extern "C" __global__ void __launch_bounds__(64) k_finalize(float* __restrict__ out){
  __shared__ double s[12];
  int t = threadIdx.x;
  if (t < 12){
    double v = 0.0;
    for (int b = 0; b < 64; ++b) v += g_part[b][t];
    s[t] = v;
  }
  __syncthreads();
  if (t == 0){
    double dt = s[0] / 4096000.0;
    double rt = s[1] / 4096000.0;
    double sp = s[2] / 4096000.0;
    double e0 = s[3] / 1024000.0, e1 = s[4] / 1024000.0;
    double e2 = s[5] / 1024000.0, e3 = s[6] / 1024000.0;
    double dec = fmax(e1 - 0.8*e0, 0.0) + fmax(e2 - 0.8*e1, 0.0) + fmax(e3 - 0.8*e2, 0.0);
    double c1 = 8240832.0;              // 64*513*251
    double freq = s[7]/c1 + 0.1*(1.0 - s[8]/c1);
    double mel  = s[9] / 1285120.0;     // 64*80*251
    double cons = s[10] / 4096000.0;
    double total = 3.0*(dt + 0.5*freq + 0.3*mel)
                 + (rt + 0.1*(sp + dec))
                 + 0.2*cons;
    out[0] = (float)total;
  }
}

extern "C" void kernel_launch(void* const* d_in, const int* in_sizes, int n_in,
                              void* d_out, int out_size, void* d_ws, size_t ws_size,
                              hipStream_t stream){
  const float* pd = (const float*)d_in[0];
  const float* pr = (const float*)d_in[1];
  const float* td = (const float*)d_in[2];
  const float* tr = (const float*)d_in[3];
  const float* mx = (const float*)d_in[4];
  float* out = (float*)d_out;
  float2* buf = (float2*)d_ws;

  size_t rowBytes = (size_t)NFB * sizeof(float2);     // 1 MiB per row
  int maxrows = (int)(ws_size / rowBytes);
  if (maxrows > ROWS) maxrows = ROWS;
  if (maxrows < 1) maxrows = 1;
  // grid-balanced chunking: chrows divides 64 so every chunk is equal
  int chrows = 1;
  const int cand[7] = {64, 32, 16, 8, 4, 2, 1};
  for (int i = 0; i < 7; ++i) if (cand[i] <= maxrows){ chrows = cand[i]; break; }

  hipLaunchKernelGGL(k_init, dim3(3), dim3(256), 0, stream);
  hipLaunchKernelGGL(k_time, dim3(2048), dim3(256), 0, stream, pd, td, pr, tr);
  hipLaunchKernelGGL(k_stft, dim3(ROWS*NFR), dim3(64), 0, stream, pd, td);
  for (int row0 = 0; row0 < ROWS; row0 += chrows){
    int nr = ROWS - row0; if (nr > chrows) nr = chrows;
    hipLaunchKernelGGL(k_fwd1, dim3(32*nr),   dim3(256), 0, stream, pd, pr, buf, row0);
    hipLaunchKernelGGL(k_mid,  dim3(129, nr), dim3(256), 0, stream, buf);
    hipLaunchKernelGGL(k_inv2, dim3(32*nr),   dim3(128), 0, stream, mx, buf, row0);
  }
  hipLaunchKernelGGL(k_finalize, dim3(1), dim3(64), 0, stream, out);
}

// Round 8
// 252.114 us; speedup vs baseline: 1.3345x; 1.0096x over previous
//
#include <hip/hip_runtime.h>
#include <math.h>

#define ROWS 64
#define TLEN 64000
#define NFR 251
#define NMELS 80
#define NFB 131072            // big FFT length (>= 2*T-1 -> exact linear conv)
#define PI2F 6.28318530717958647692f
#define PI_F 3.14159265358979323846f

// banked double accumulators:
// 0 S_dt  1 S_rt  2 S_sp  3..6 E0..E3  7 S_mag  8 S_cos  9 S_mel  10 S_c
__device__ double g_part[64][12];

// slot holding k2 after per-lane radix-4 FFT16 (digit reversal, involution)
__device__ constexpr int DR[16] = {0,4,8,12,1,5,9,13,2,6,10,14,3,7,11,15};
// mirror slot: RM[r] = DR[16 - DR[r]]
__device__ constexpr int RM[16] = {0,3,2,1,15,14,13,12,11,10,9,8,7,6,5,4};

__device__ inline int dr4(int i){ return ((i & 3) << 2) | (i >> 2); }  // DR, runtime
// bank-conflict-free swizzle for stride-16 writes into 513-entry arrays
__device__ inline int SW(int k){ return k + (k >> 5); }

__device__ inline void atomAddD(double* p, double v){
  __hip_atomic_fetch_add(p, v, __ATOMIC_RELAXED, __HIP_MEMORY_SCOPE_AGENT);
}
__device__ inline int brev6(int x){ return (int)((unsigned)__brev((unsigned)x) >> 26); }
__device__ inline float2 cmul(float2 a, float2 b){
  return make_float2(a.x*b.x - a.y*b.y, a.x*b.y + a.y*b.x);
}
__device__ inline float wred(float v){
#pragma unroll
  for (int o = 32; o > 0; o >>= 1) v += __shfl_down(v, o, 64);
  return v;
}

// wave-local LDS fence: DS traffic inside fft64_ldsn is per-wave cross-lane ->
// only this wave's lgkmcnt needs draining, NOT a workgroup barrier.
__device__ inline void wave_fence(){
  asm volatile("s_waitcnt lgkmcnt(0)" ::: "memory");
}

template<int S>
__device__ inline void fft16_reg(float2* v){
  const float Sf = (float)S;
  const float C1 = 0.9238795325112867f, S1 = 0.3826834323650898f, C2 = 0.7071067811865476f;
  const float2 W1[4] = {{1.f,0.f},{C1,Sf*S1},{C2,Sf*C2},{S1,Sf*C1}};
  const float2 W2[4] = {{1.f,0.f},{C2,Sf*C2},{0.f,Sf},{-C2,Sf*C2}};
  const float2 W3[4] = {{1.f,0.f},{S1,Sf*C1},{-C2,Sf*C2},{-C1,-Sf*S1}};
#pragma unroll
  for (int j = 0; j < 4; ++j){
    float2 x0=v[j], x1=v[j+4], x2=v[j+8], x3=v[j+12];
    float2 t0={x0.x+x2.x, x0.y+x2.y}, t1={x0.x-x2.x, x0.y-x2.y};
    float2 t2={x1.x+x3.x, x1.y+x3.y}, t3={x1.x-x3.x, x1.y-x3.y};
    float2 y0={t0.x+t2.x, t0.y+t2.y};
    float2 y2={t0.x-t2.x, t0.y-t2.y};
    float2 y1={t1.x - Sf*t3.y, t1.y + Sf*t3.x};
    float2 y3={t1.x + Sf*t3.y, t1.y - Sf*t3.x};
    v[j]=y0; v[j+4]=cmul(y1,W1[j]); v[j+8]=cmul(y2,W2[j]); v[j+12]=cmul(y3,W3[j]);
  }
#pragma unroll
  for (int b = 0; b < 4; ++b){
    float2 x0=v[4*b], x1=v[4*b+1], x2=v[4*b+2], x3=v[4*b+3];
    float2 t0={x0.x+x2.x, x0.y+x2.y}, t1={x0.x-x2.x, x0.y-x2.y};
    float2 t2={x1.x+x3.x, x1.y+x3.y}, t3={x1.x-x3.x, x1.y-x3.y};
    v[4*b]   = make_float2(t0.x+t2.x, t0.y+t2.y);
    v[4*b+2] = make_float2(t0.x-t2.x, t0.y-t2.y);
    v[4*b+1] = make_float2(t1.x - Sf*t3.y, t1.y + Sf*t3.x);
    v[4*b+3] = make_float2(t1.x + Sf*t3.y, t1.y - Sf*t3.x);
  }
}

// ---------- LDS-based cross-lane 64-FFT (four-step 8x8), natural in/out ----------
template<int S>
__device__ inline void fft8p(float2* y){
  const float Sf = (float)S;
  const float C2 = 0.7071067811865476f;
  float2 t0={y[0].x+y[4].x, y[0].y+y[4].y};
  float2 t1={y[1].x+y[5].x, y[1].y+y[5].y};
  float2 t2={y[2].x+y[6].x, y[2].y+y[6].y};
  float2 t3={y[3].x+y[7].x, y[3].y+y[7].y};
  float2 u0={y[0].x-y[4].x, y[0].y-y[4].y};
  float2 u1={y[1].x-y[5].x, y[1].y-y[5].y};
  float2 u2={y[2].x-y[6].x, y[2].y-y[6].y};
  float2 u3={y[3].x-y[7].x, y[3].y-y[7].y};
  { float x=u1.x, yy=u1.y; u1.x = C2*(x - Sf*yy); u1.y = C2*(Sf*x + yy); }
  { float x=u2.x, yy=u2.y; u2.x = -Sf*yy;         u2.y = Sf*x; }
  { float x=u3.x, yy=u3.y; u3.x = -C2*(x + Sf*yy); u3.y = C2*(Sf*x - yy); }
  {
    float2 e0={t0.x+t2.x,t0.y+t2.y}, e1={t0.x-t2.x,t0.y-t2.y};
    float2 o0={t1.x+t3.x,t1.y+t3.y}, o1={t1.x-t3.x,t1.y-t3.y};
    y[0]=make_float2(e0.x+o0.x, e0.y+o0.y);
    y[4]=make_float2(e0.x-o0.x, e0.y-o0.y);
    y[2]=make_float2(e1.x - Sf*o1.y, e1.y + Sf*o1.x);
    y[6]=make_float2(e1.x + Sf*o1.y, e1.y - Sf*o1.x);
  }
  {
    float2 e0={u0.x+u2.x,u0.y+u2.y}, e1={u0.x-u2.x,u0.y-u2.y};
    float2 o0={u1.x+u3.x,u1.y+u3.y}, o1={u1.x-u3.x,u1.y-u3.y};
    y[1]=make_float2(e0.x+o0.x, e0.y+o0.y);
    y[5]=make_float2(e0.x-o0.x, e0.y-o0.y);
    y[3]=make_float2(e1.x - Sf*o1.y, e1.y + Sf*o1.x);
    y[7]=make_float2(e1.x + Sf*o1.y, e1.y - Sf*o1.x);
  }
}

// NS independent 64-pt FFTs across lanes (NS = 8 or 16), natural lane order
// in AND out, 8 slots per pass through a per-wave 4KB scratch (scr[512]).
template<int S, int NS>
__device__ inline void fft64_ldsn(float2* v, int l, float2* scr){
  int s = l >> 3, a = l & 7;
  int sw = (s & 1);
#pragma unroll
  for (int h = 0; h < NS/8; ++h){
    float2* vh = v + 8*h;
#pragma unroll
    for (int r = 0; r < 8; ++r) scr[r*64 + l] = vh[r];
    wave_fence();
    float2 y[8];
#pragma unroll
    for (int j = 0; j < 8; ++j)
      y[j] = scr[s*64 + a + 8*((j + s) & 7)];
    fft8p<S>(y);
    {
      float ang = (float)S * PI2F * (float)l * (1.0f/64.0f);
      float sn, cs; __sincosf(ang, &sn, &cs);
      float2 b1 = make_float2(cs, sn), cur = b1;
#pragma unroll
      for (int c = 1; c < 8; ++c){
        y[c] = cmul(y[c], cur);
        if (c < 7) cur = cmul(cur, b1);
      }
    }
    wave_fence();
#pragma unroll
    for (int c = 0; c < 8; ++c)
      scr[s*64 + a + 8*(c ^ sw)] = y[c];
    wave_fence();
    float2 z[8];
#pragma unroll
    for (int j = 0; j < 8; ++j)
      z[j] = scr[s*64 + ((j + s) & 7) + 8*(a ^ sw)];
    fft8p<S>(z);
    {
      float ang2 = (float)S * PI2F * (float)s * 0.125f;
      float sn2, cs2; __sincosf(ang2, &sn2, &cs2);
      float2 b2 = make_float2(cs2, sn2), cur = b2;
#pragma unroll
      for (int d = 1; d < 8; ++d){
        z[d] = cmul(z[d], cur);
        if (d < 7) cur = cmul(cur, b2);
      }
    }
    wave_fence();
#pragma unroll
    for (int d = 0; d < 8; ++d)
      scr[s*64 + a + 8*(d ^ sw)] = z[d];
    wave_fence();
#pragma unroll
    for (int r = 0; r < 8; ++r)
      vh[r] = scr[r*64 + (l ^ ((r & 1) << 3))];
    wave_fence();
  }
}

// 1024-pt forward via LDS: input v[m]=x[l+64m]; output slot rr, lane l =
// X[DR[rr] + 16*l]   (NATURAL lane order)
template<int S>
__device__ inline void fft1024_lds(float2* v, int l, float2* scr){
  fft16_reg<S>(v);
  float a = (float)S * PI2F * (float)l * (1.0f/1024.0f);
  float sn, cs; __sincosf(a, &sn, &cs);
  float2 T = make_float2(cs, sn);
  float2 cur = T;
#pragma unroll
  for (int k2 = 1; k2 < 16; ++k2){
    v[DR[k2]] = cmul(v[DR[k2]], cur);
    if (k2 < 15) cur = cmul(cur, T);
  }
  fft64_ldsn<S,16>(v, l, scr);
}

__device__ inline void r4p(float2* v, int i0, int i1, int i2, int i3){
  float2 x0=v[i0], x1=v[i1], x2=v[i2], x3=v[i3];
  float2 t0={x0.x+x2.x, x0.y+x2.y}, t1={x0.x-x2.x, x0.y-x2.y};
  float2 t2={x1.x+x3.x, x1.y+x3.y}, t3={x1.x-x3.x, x1.y-x3.y};
  v[i0] = make_float2(t0.x+t2.x, t0.y+t2.y);
  v[i2] = make_float2(t0.x-t2.x, t0.y-t2.y);
  v[i1] = make_float2(t1.x - t3.y, t1.y + t3.x);
  v[i3] = make_float2(t1.x + t3.y, t1.y - t3.x);
}

__device__ inline void ifft16_reg(float2* v){
#pragma unroll
  for (int b = 0; b < 4; ++b) r4p(v, 4*b, 4*b+1, 4*b+2, 4*b+3);
  const float C1 = 0.9238795325112867f, S1 = 0.3826834323650898f, C2 = 0.7071067811865476f;
  const float2 W1[4] = {{1.f,0.f},{C1,S1},{C2,C2},{S1,C1}};
  const float2 W2[4] = {{1.f,0.f},{C2,C2},{0.f,1.f},{-C2,C2}};
  const float2 W3[4] = {{1.f,0.f},{S1,C1},{-C2,C2},{-C1,-S1}};
#pragma unroll
  for (int j = 1; j < 4; ++j){
    v[j+4]  = cmul(v[j+4],  W1[j]);
    v[j+8]  = cmul(v[j+8],  W2[j]);
    v[j+12] = cmul(v[j+12], W3[j]);
  }
#pragma unroll
  for (int j = 0; j < 4; ++j) r4p(v, j, j+4, j+8, j+12);
}

__device__ inline void ifft1024_lds(float2* v, int l, float2* scr){
  fft64_ldsn<1,16>(v, l, scr);        // inverse 64-FFT over lanes, natural order
  float a = PI2F * (float)l * (1.0f/1024.0f);
  float sn, cs; __sincosf(a, &sn, &cs);
  float2 T = make_float2(cs, sn);
  float2 cur = T;
#pragma unroll
  for (int k2 = 1; k2 < 16; ++k2){
    v[DR[k2]] = cmul(v[DR[k2]], cur);
    if (k2 < 15) cur = cmul(cur, T);
  }
  ifft16_reg(v);
}

// ---------------- init: zero accumulators ----------------
extern "C" __global__ void __launch_bounds__(256) k_init(){
  int t = blockIdx.x*256 + threadIdx.x;
  if (t < 768) ((double*)g_part)[t] = 0.0;
}

// ---------------- time-domain losses + rir segment energies (float4) -------
extern "C" __global__ void __launch_bounds__(256) k_time(
    const float* __restrict__ pd, const float* __restrict__ td,
    const float* __restrict__ pr, const float* __restrict__ tr){
  const int N4 = ROWS*TLEN/4;          // 1,024,000 float4s; 16000 per row
  int stride = gridDim.x * 256;
  float sdt=0.f, srt=0.f, ssp=0.f, e0=0.f, e1=0.f, e2=0.f, e3=0.f;
  const float4* pd4 = (const float4*)pd;
  const float4* td4 = (const float4*)td;
  const float4* pr4 = (const float4*)pr;
  const float4* tr4 = (const float4*)tr;
  for (int i = blockIdx.x*256 + threadIdx.x; i < N4; i += stride){
    float4 a = pd4[i], b = td4[i], p = pr4[i], q = tr4[i];
    sdt += fabsf(a.x-b.x)+fabsf(a.y-b.y)+fabsf(a.z-b.z)+fabsf(a.w-b.w);
    srt += fabsf(p.x-q.x)+fabsf(p.y-q.y)+fabsf(p.z-q.z)+fabsf(p.w-q.w);
    ssp += fabsf(p.x)+fabsf(p.y)+fabsf(p.z)+fabsf(p.w);
    float p2 = p.x*p.x + p.y*p.y + p.z*p.z + p.w*p.w;
    int seg = (i % 16000) / 4000;      // uniform for all 4 elems
    if (seg == 0) e0 += p2; else if (seg == 1) e1 += p2;
    else if (seg == 2) e2 += p2; else e3 += p2;
  }
  sdt = wred(sdt); srt = wred(srt); ssp = wred(ssp);
  e0 = wred(e0); e1 = wred(e1); e2 = wred(e2); e3 = wred(e3);
  if ((threadIdx.x & 63) == 0){
    int bank = (blockIdx.x*4 + (threadIdx.x >> 6)) & 63;
    atomAddD(&g_part[bank][0], (double)sdt);
    atomAddD(&g_part[bank][1], (double)srt);
    atomAddD(&g_part[bank][2], (double)ssp);
    atomAddD(&g_part[bank][3], (double)e0);
    atomAddD(&g_part[bank][4], (double)e1);
    atomAddD(&g_part[bank][5], (double)e2);
    atomAddD(&g_part[bank][6], (double)e3);
  }
}

// ---------------- fused STFT (freq + mel) losses, ONE WAVE PER BLOCK --------
extern "C" __global__ void __launch_bounds__(64) k_stft(
    const float* __restrict__ pd, const float* __restrict__ td){
  __shared__ float2 scr[512];             // 4KB four-step scratch
  __shared__ float2 spec0[64];
  __shared__ float2 pt[530];              // (pp,tt) pairs, swizzled SW(k)=k+(k>>5)
  int l = threadIdx.x;
  // XCD-aware swizzle: 16064 = 8*2008 exactly; consecutive frames on same XCD
  int frame = (blockIdx.x & 7) * (ROWS*NFR/8) + (blockIdx.x >> 3);
  int r = frame / NFR, fr = frame - r*NFR;
  const float* pdr = pd + (size_t)r*TLEN;
  const float* tdr = td + (size_t)r*TLEN;
  const float scale = 0.05103103630798288f;   // 1/sqrt(384), folded into window
  int base = fr*256 - 512;
  float2 v[16];
#pragma unroll
  for (int m = 0; m < 16; ++m){
    int j = l + 64*m;
    int g = base + j;
    g = (g < 0) ? -g : ((g >= TLEN) ? (2*TLEN - 2 - g) : g);
    float w = (0.5f - 0.5f*__cosf((PI2F/1024.0f)*(float)j)) * scale;
    v[m] = make_float2(pdr[g]*w, tdr[g]*w);
  }
  fft1024_lds<-1>(v, l, scr);
  // output: slot rr, lane l = X[DR[rr] + 16*l]  (natural lane order)
  spec0[l] = v[0];          // the k2=0 line: Z[16*k1] at index k1
  float magp = 0.f, cosp = 0.f;
  // k2 = 1..15 lines: mirror of (slot rr, lane l) is (slot RM[rr], lane l^63).
#pragma unroll
  for (int rr = 1; rr < 16; ++rr){
    float2 z = v[rr];
    float2 zm;
    zm.x = __shfl_xor(v[RM[rr]].x, 63, 64);
    zm.y = __shfl_xor(v[RM[rr]].y, 63, 64);
    int k = DR[rr] + 16*l;
    float px = 0.5f*(z.x + zm.x), py = 0.5f*(z.y - zm.y);
    float tx = 0.5f*(z.y + zm.y), ty = -0.5f*(z.x - zm.x);
    float ppk = px*px + py*py, ttk = tx*tx + ty*ty;
    float rp = rsqrtf(fmaxf(ppk, 1e-30f)), rt = rsqrtf(fmaxf(ttk, 1e-30f));
    magp += 0.5f*fabsf(ppk*rp - ttk*rt);
    cosp += 0.5f*((px*tx + py*ty)*rp*rt);
    int kk = (k <= 512) ? k : 1024 - k;
    pt[SW(kk)] = make_float2(ppk, ttk);
  }
  if (l <= 32){                    // k = 16*l, weight 1
    float2 z  = spec0[l];
    float2 zm = spec0[(64 - l) & 63];
    float px = 0.5f*(z.x + zm.x), py = 0.5f*(z.y - zm.y);
    float tx = 0.5f*(z.y + zm.y), ty = -0.5f*(z.x - zm.x);
    float ppk = px*px + py*py, ttk = tx*tx + ty*ty;
    float rp = rsqrtf(fmaxf(ppk, 1e-30f)), rt = rsqrtf(fmaxf(ttk, 1e-30f));
    magp += fabsf(ppk*rp - ttk*rt);
    cosp += (px*tx + py*ty)*rp*rt;
    pt[SW(16*l)] = make_float2(ppk, ttk);
  }
  float melp = 0.f;
  const float C = (2595.0f * log10f(1.0f + 8000.0f/700.0f))
                  * (1.0f/81.0f) * (1.0f/2595.0f) * 2.302585093f;
  const float df = 15.625f;
  {
    int m = l;                       // P0: mel m = lane
    float f0 = 700.0f*(__expf(C*(float)(m  )) - 1.0f);
    float f1 = 700.0f*(__expf(C*(float)(m+1)) - 1.0f);
    float f2 = 700.0f*(__expf(C*(float)(m+2)) - 1.0f);
    float i1 = 1.0f/(f1 - f0), i2 = 1.0f/(f2 - f1);
    int lo = (int)ceilf(f0 * (1.0f/df));  if (lo < 0) lo = 0;
    int hi = (int)floorf(f2 * (1.0f/df)); if (hi > 512) hi = 512;
    float pm = 0.f, tm = 0.f;
#pragma unroll 2
    for (int k = lo; k <= hi; ++k){
      float frq = df*(float)k;
      float c = fmaxf(fminf((frq - f0)*i1, (f2 - frq)*i2), 0.f);
      float2 w = pt[SW(k)];
      pm += c*w.x; tm += c*w.y;
    }
    melp += fabsf(__logf(pm + 1e-8f) - __logf(tm + 1e-8f));
  }
  {
    int m = 64 + (l >> 2), q = l & 3;  // P1: 4 lanes per wide mel
    float f0 = 700.0f*(__expf(C*(float)(m  )) - 1.0f);
    float f1 = 700.0f*(__expf(C*(float)(m+1)) - 1.0f);
    float f2 = 700.0f*(__expf(C*(float)(m+2)) - 1.0f);
    float i1 = 1.0f/(f1 - f0), i2 = 1.0f/(f2 - f1);
    int lo = (int)ceilf(f0 * (1.0f/df));  if (lo < 0) lo = 0;
    int hi = (int)floorf(f2 * (1.0f/df)); if (hi > 512) hi = 512;
    int n = hi - lo + 1;
    int ch = (n + 3) >> 2;
    int k0 = lo + q*ch;
    int k1 = k0 + ch; if (k1 > hi + 1) k1 = hi + 1;
    float pm = 0.f, tm = 0.f;
#pragma unroll 2
    for (int k = k0; k < k1; ++k){
      float frq = df*(float)k;
      float c = fmaxf(fminf((frq - f0)*i1, (f2 - frq)*i2), 0.f);
      float2 w = pt[SW(k)];
      pm += c*w.x; tm += c*w.y;
    }
    pm += __shfl_xor(pm, 1, 64); pm += __shfl_xor(pm, 2, 64);
    tm += __shfl_xor(tm, 1, 64); tm += __shfl_xor(tm, 2, 64);
    if (q == 0)
      melp += fabsf(__logf(pm + 1e-8f) - __logf(tm + 1e-8f));
  }
  magp = wred(magp); cosp = wred(cosp); melp = wred(melp);
  if (l == 0){
    int bank = blockIdx.x & 63;
    atomAddD(&g_part[bank][7], (double)magp);
    atomAddD(&g_part[bank][8], (double)cosp);
    atomAddD(&g_part[bank][9], (double)melp);
  }
}

// ---------------- consistency: four-step FFT of 131072 = 128 x 1024 ---------
// n = n1 + 128*n2 ; storage: buf[s*128 + n1], s = rr*64 + l holds spectral
// line K = DR[rr] + 16*l  (natural lane order after the LDS 1024-FFT).
// fwd1: 4-wave blocks (4 n1 each), 1D grid with XCD-locality remap.
extern "C" __global__ void __launch_bounds__(256) k_fwd1(
    const float* __restrict__ pd, const float* __restrict__ pr,
    float2* __restrict__ buf, int row0){
  __shared__ float SM[6144];                     // 24 KB
  float* LA = SM;                                // [500][6] floats (a)
  float* LB = SM + 3000;                         // [500][6] floats (b)
  float2* LT = (float2*)SM;                      // [4][513] float2 (chunks)
  int wid = threadIdx.x >> 6, l = threadIdx.x & 63;
  int tid = threadIdx.x;
  float2* scr = (float2*)SM + (size_t)wid*512;   // per-wave 4KB fft scratch
  int flat = blockIdx.x;
  int cpx = gridDim.x >> 3;                      // gridDim.x = 32*nr, 8 | 32
  int w = (flat & 7) * cpx + (flat >> 3);
  int rl = w >> 5;
  int n1base = (w & 31) * 4;
  int n1 = n1base + wid;
  const float* a = pd + (size_t)(row0+rl)*TLEN;
  const float* b = pr + (size_t)(row0+rl)*TLEN;
  for (int i = tid; i < 1000; i += 256){
    int n2 = i >> 1, wp = (i & 1)*2;
    float2 va = *(const float2*)&a[n1base + wp + 128*n2];
    float2 vb = *(const float2*)&b[n1base + wp + 128*n2];
    *(float2*)&LA[n2*6 + wp] = va;
    *(float2*)&LB[n2*6 + wp] = vb;
  }
  __syncthreads();
  float2 v[16];
#pragma unroll
  for (int m = 0; m < 16; ++m){
    int n2 = l + 64*m;
    if (n2 < 500) v[m] = make_float2(LA[n2*6 + wid], LB[n2*6 + wid]);
    else          v[m] = make_float2(0.f, 0.f);
  }
  __syncthreads();                                // LA/LB reads done (scr aliases)
  fft1024_lds<-1>(v, l, scr);
  const float tw = -(PI2F / (float)NFB);
#pragma unroll
  for (int rr = 0; rr < 16; ++rr){
    int K = DR[rr] + 16*l;
    float ang = tw * (float)(n1*K);               // n1*K < 2^24: exact
    float sn, cs; __sincosf(ang, &sn, &cs);
    v[rr] = cmul(v[rr], make_float2(cs, sn));
  }
  float2* rowp = buf + (size_t)rl*NFB;
  __syncthreads();                                // all waves done with scr
#pragma unroll
  for (int c = 0; c < 2; ++c){
#pragma unroll
    for (int rrl = 0; rrl < 8; ++rrl)
      LT[wid*513 + rrl*64 + l] = v[c*8 + rrl];
    __syncthreads();
#pragma unroll
    for (int it = 0; it < 4; ++it){
      int idx = tid + it*256;                     // 1024 float4s per chunk
      int s = idx >> 1, nw = (idx & 1)*2;         // s in [0,512), nw in {0,2}
      float2 x = LT[nw*513 + s], y = LT[(nw+1)*513 + s];
      *(float4*)&rowp[(size_t)(c*512 + s)*128 + n1base + nw] =
          make_float4(x.x, x.y, y.x, y.y);
    }
    __syncthreads();
  }
}

// D/R split + product for one element (z) given its mirror partner (zm)
__device__ inline float2 pointmul(float2 z, float2 zm){
  float Dx = 0.5f*(z.x + zm.x), Dy = 0.5f*(z.y - zm.y);
  float Rx = 0.5f*(z.y + zm.y), Ry = -0.5f*(z.x - zm.x);
  return make_float2(Dx*Rx - Dy*Ry, Dx*Ry + Dy*Rx);
}

// k_mid: fused fwd2 + pointwise + inv1 via the LDS four-step machinery.
// Each WAVE batches 4 K-pairs (8 rows = 16 slots): register radix-2+twiddle,
// then ONE fft64_ldsn<-1,16> does all eight 128-pt forward FFTs in natural
// order (slot parity rr, lane l = X[rr+2l]; mirror = (1-rr, l^63)).
// Pointwise -> 8 slots -> fft64_ldsn<1,8> inverse -> register combine.
// CONJ-STORAGE: only rows K<=512 are written; mirrors reconstructed in inv2.
extern "C" __global__ void __launch_bounds__(256) k_mid(float2* __restrict__ buf){
  __shared__ float2 SCR[2048];                   // 4 waves x 4KB
  int wid = threadIdx.x >> 6, l = threadIdx.x & 63;
  float2* scr = SCR + (size_t)wid*512;
  float2* base = buf + (size_t)blockIdx.y*NFB;
  int p0 = (blockIdx.x*4 + wid)*4;               // first pair of this wave
  float2 v[16];
  int sAr[4];
#pragma unroll
  for (int j = 0; j < 4; ++j){
    int p = p0 + j;
    bool ok = (p <= 512);
    int k2A = ok ? p : 0;
    int k2B = (1024 - k2A) & 1023;
    int sA = dr4(k2A & 15)*64 + (k2A >> 4);
    int sB = dr4(k2B & 15)*64 + (k2B >> 4);
    sAr[j] = sA;
    if (ok){
      const float2* rA = base + (size_t)sA*128;
      v[4*j+0] = rA[l]; v[4*j+1] = rA[l+64];
      if (sB != sA){
        const float2* rB = base + (size_t)sB*128;
        v[4*j+2] = rB[l]; v[4*j+3] = rB[l+64];
      } else {
        v[4*j+2] = make_float2(0.f,0.f); v[4*j+3] = make_float2(0.f,0.f);
      }
    } else {
      v[4*j+0]=v[4*j+1]=v[4*j+2]=v[4*j+3]=make_float2(0.f,0.f);
    }
  }
  // radix-2 + twiddle: slot pair (2i,2i+1) holds one 128-pt input x[l+64m]
  {
    float ang = -PI_F * (float)l * (1.0f/64.0f);
    float sn, cs; __sincosf(ang, &sn, &cs);
    float2 W = make_float2(cs, sn);
#pragma unroll
    for (int i = 0; i < 8; ++i){
      float2 x0 = v[2*i], x1 = v[2*i+1];
      float2 aa = {x0.x+x1.x, x0.y+x1.y};
      float2 bb = {x0.x-x1.x, x0.y-x1.y};
      v[2*i] = aa; v[2*i+1] = cmul(bb, W);
    }
  }
  fft64_ldsn<-1,16>(v, l, scr);
  // slot (4j+rr) = XA_j[rr+2l]; slot (4j+2+rr) = XB_j[rr+2l]
  float2 ci[8];
#pragma unroll
  for (int j = 0; j < 4; ++j){
    int p = p0 + j;
    float2 zm0, zm1;
    if (p == 0){
      int q0 = (64 - l) & 63;
      zm0.x = __shfl(v[0].x, q0, 64); zm0.y = __shfl(v[0].y, q0, 64);
      zm1.x = __shfl_xor(v[1].x, 63, 64); zm1.y = __shfl_xor(v[1].y, 63, 64);
    } else if (p == 512){
      zm0.x = __shfl_xor(v[4*j+1].x, 63, 64); zm0.y = __shfl_xor(v[4*j+1].y, 63, 64);
      zm1.x = __shfl_xor(v[4*j+0].x, 63, 64); zm1.y = __shfl_xor(v[4*j+0].y, 63, 64);
    } else {
      zm0.x = __shfl_xor(v[4*j+3].x, 63, 64); zm0.y = __shfl_xor(v[4*j+3].y, 63, 64);
      zm1.x = __shfl_xor(v[4*j+2].x, 63, 64); zm1.y = __shfl_xor(v[4*j+2].y, 63, 64);
    }
    ci[2*j]   = pointmul(v[4*j+0], zm0);
    ci[2*j+1] = pointmul(v[4*j+1], zm1);
  }
  fft64_ldsn<1,8>(ci, l, scr);
  // combine (E +/- W128^l * O) = 128*x[l], 128*x[l+64]; final twiddle; store A
  {
    float angw = PI_F * (float)l * (1.0f/64.0f);
    float snw, csw; __sincosf(angw, &snw, &csw);
    float2 W = make_float2(csw, snw);
    const float twi = PI2F / (float)NFB;
#pragma unroll
    for (int j = 0; j < 4; ++j){
      int p = p0 + j;
      if (p > 512) continue;
      float2 E = ci[2*j], O = cmul(ci[2*j+1], W);
      float2 o0 = {E.x+O.x, E.y+O.y};
      float2 o1 = {E.x-O.x, E.y-O.y};
      float2* rA = base + (size_t)sAr[j]*128;
      { float ang = twi * (float)(l*p); float sn, cs; __sincosf(ang, &sn, &cs);
        rA[l] = cmul(o0, make_float2(cs, sn)); }
      { float ang = twi * (float)((l+64)*p); float sn, cs; __sincosf(ang, &sn, &cs);
        rA[l+64] = cmul(o1, make_float2(cs, sn)); }
    }
  }
}

// inv2: column-PAIRED adjoint inverse 1024-pt FFTs; 2-wave blocks (4 cols).
// XCD-locality remap as in fwd1. CONJ-STORAGE readback: storage positions
// with K>512 are reconstructed from the stored mirror row (K'=1024-K) via
// Z = conj(A') + i*conj(B') = (x+w, z-y).
extern "C" __global__ void __launch_bounds__(128) k_inv2(
    const float* __restrict__ mix, float2* __restrict__ buf, int row0){
  __shared__ float SM[5052];                     // 20.2 KB, aliased phases
  float2* LT = (float2*)SM;                      // [2][513] f2, packed Z
  float* LM = SM + 2052;                         // [500][6] floats (mix)
  int wid = threadIdx.x >> 6, l = threadIdx.x & 63;
  int tid = threadIdx.x;
  float2* scr = (float2*)SM + (size_t)wid*512;   // per-wave 4KB fft scratch
  int flat = blockIdx.x;
  int cpx = gridDim.x >> 3;                      // gridDim.x = 32*nr
  int w = (flat & 7) * cpx + (flat >> 3);
  int rl = w >> 5;
  int n1base = (w & 31) * 4;
  float2* rowp = buf + (size_t)rl*NFB;
  float2 v[16];
#pragma unroll
  for (int c = 0; c < 2; ++c){
#pragma unroll
    for (int it = 0; it < 8; ++it){
      int idx = tid + it*128;                     // 1024 float4s per chunk
      int s = idx >> 1, nw = (idx & 1)*2;         // s in [0,512), nw in {0,2}
      int srow = c*512 + s;
      int rr = srow >> 6, lr = srow & 63;
      int d = dr4(rr);
      int K = d + 16*lr;
      bool mir = (K > 512);
      int srcrow = mir ? (dr4((16 - d) & 15)*64 + (64 - lr - (d > 0 ? 1 : 0)))
                       : srow;
      float4 q = *(const float4*)&rowp[(size_t)srcrow*128 + n1base + nw];
      LT[(nw >> 1)*513 + s] = mir ? make_float2(q.x + q.w, q.z - q.y)
                                  : make_float2(q.x - q.w, q.y + q.z);
    }
    __syncthreads();
#pragma unroll
    for (int rrl = 0; rrl < 8; ++rrl)
      v[c*8 + rrl] = LT[wid*513 + rrl*64 + l];
    __syncthreads();                              // LT reads done before reuse
  }
  const float* mr = mix + (size_t)(row0+rl)*TLEN;
  for (int i = tid; i < 1000; i += 128){
    int n2 = i >> 1, wp = (i & 1)*2;
    *(float2*)&LM[n2*6 + wp] = *(const float2*)&mr[n1base + wp + 128*n2];
  }
  ifft1024_lds(v, l, scr);
  __syncthreads();                                // LM ready
  const float invn = 1.0f/(float)NFB;
  float acc = 0.f;
#pragma unroll
  for (int m = 0; m < 16; ++m){
    int n2 = l + 64*m;
    if (n2 < 500){
      float2 mm = *(const float2*)&LM[n2*6 + 2*wid];
      acc += fabsf(v[m].x*invn - mm.x) + fabsf(v[m].y*invn - mm.y);
    }
  }
  acc = wred(acc);
  if (l == 0){
    int bank = (flat*2 + wid) & 63;
    atomAddD(&g_part[bank][10], (double)acc);
  }
}

// ---------------- combine ----------------
extern "C" __global__ void __launch_bounds__(64) k_finalize(float* __restrict__ out){
  __shared__ double s[12];
  int t = threadIdx.x;
  if (t < 12){
    double v = 0.0;
    for (int b = 0; b < 64; ++b) v += g_part[b][t];
    s[t] = v;
  }
  __syncthreads();
  if (t == 0){
    double dt = s[0] / 4096000.0;
    double rt = s[1] / 4096000.0;
    double sp = s[2] / 4096000.0;
    double e0 = s[3] / 1024000.0, e1 = s[4] / 1024000.0;
    double e2 = s[5] / 1024000.0, e3 = s[6] / 1024000.0;
    double dec = fmax(e1 - 0.8*e0, 0.0) + fmax(e2 - 0.8*e1, 0.0) + fmax(e3 - 0.8*e2, 0.0);
    double c1 = 8240832.0;              // 64*513*251
    double freq = s[7]/c1 + 0.1*(1.0 - s[8]/c1);
    double mel  = s[9] / 1285120.0;     // 64*80*251
    double cons = s[10] / 4096000.0;
    double total = 3.0*(dt + 0.5*freq + 0.3*mel)
                 + (rt + 0.1*(sp + dec))
                 + 0.2*cons;
    out[0] = (float)total;
  }
}

extern "C" void kernel_launch(void* const* d_in, const int* in_sizes, int n_in,
                              void* d_out, int out_size, void* d_ws, size_t ws_size,
                              hipStream_t stream){
  const float* pd = (const float*)d_in[0];
  const float* pr = (const float*)d_in[1];
  const float* td = (const float*)d_in[2];
  const float* tr = (const float*)d_in[3];
  const float* mx = (const float*)d_in[4];
  float* out = (float*)d_out;
  float2* buf = (float2*)d_ws;

  size_t rowBytes = (size_t)NFB * sizeof(float2);     // 1 MiB per row
  int maxrows = (int)(ws_size / rowBytes);
  if (maxrows > ROWS) maxrows = ROWS;
  if (maxrows < 1) maxrows = 1;
  // grid-balanced chunking: chrows divides 64 so every chunk is equal
  int chrows = 1;
  const int cand[7] = {64, 32, 16, 8, 4, 2, 1};
  for (int i = 0; i < 7; ++i) if (cand[i] <= maxrows){ chrows = cand[i]; break; }

  hipLaunchKernelGGL(k_init, dim3(3), dim3(256), 0, stream);
  hipLaunchKernelGGL(k_time, dim3(2048), dim3(256), 0, stream, pd, td, pr, tr);
  hipLaunchKernelGGL(k_stft, dim3(ROWS*NFR), dim3(64), 0, stream, pd, td);
  for (int row0 = 0; row0 < ROWS; row0 += chrows){
    int nr = ROWS - row0; if (nr > chrows) nr = chrows;
    hipLaunchKernelGGL(k_fwd1, dim3(32*nr),  dim3(256), 0, stream, pd, pr, buf, row0);
    hipLaunchKernelGGL(k_mid,  dim3(33, nr), dim3(256), 0, stream, buf);
    hipLaunchKernelGGL(k_inv2, dim3(32*nr),  dim3(128), 0, stream, mx, buf, row0);
  }
  hipLaunchKernelGGL(k_finalize, dim3(1), dim3(64), 0, stream, out);
}